// Round 1
// baseline (2656.780 us; speedup 1.0000x reference)
//
#include <hip/hip_runtime.h>

// Problem constants (RelationalAttentionLayer)
#define N_NODES 50000
#define DIM     128
#define HEADS   4
#define HDIM    512      // HEADS * DIM
#define NREL    3
#define NEDGE   50000    // edges per relation
// total edges = NREL * NEDGE = 150000

constexpr float EPS_F  = 1e-10f;
constexpr float SCALE  = 0.044194173824159216f;  // 1/sqrt(512)

// ---------------------------------------------------------------------------
// Generic f32 GEMM: C[M,Nn] = A[M,K] @ B[K,Nn]
// 64x64 tile, BK=32, 256 threads, 4x4 per-thread tile. M may be ragged.
// ---------------------------------------------------------------------------
__global__ __launch_bounds__(256) void gemm_f32(const float* __restrict__ A,
                                                const float* __restrict__ B,
                                                float* __restrict__ C,
                                                int M, int Nn, int K)
{
    __shared__ float As[64][36];   // [row][k], pad 36 -> 144B row stride (16B aligned)
    __shared__ float Bs[32][64];   // [k][col]

    const int tid = threadIdx.x;
    const int bm = blockIdx.x, bn = blockIdx.y;
    const int ty = tid >> 4, tx = tid & 15;

    int arow[2];
#pragma unroll
    for (int p = 0; p < 2; ++p) {
        int r = bm * 64 + p * 32 + (tid >> 3);
        arow[p] = (r < M) ? r : (M - 1);
    }

    float acc[4][4] = {};

    for (int kk = 0; kk < K; kk += 32) {
        __syncthreads();
#pragma unroll
        for (int p = 0; p < 2; ++p) {
            int row = p * 32 + (tid >> 3);
            int k4  = (tid & 7) * 4;
            float4 v = *reinterpret_cast<const float4*>(&A[(size_t)arow[p] * K + kk + k4]);
            *reinterpret_cast<float4*>(&As[row][k4]) = v;
        }
#pragma unroll
        for (int p = 0; p < 2; ++p) {
            int kr = p * 16 + (tid >> 4);
            int c4 = (tid & 15) * 4;
            *reinterpret_cast<float4*>(&Bs[kr][c4]) =
                *reinterpret_cast<const float4*>(&B[(size_t)(kk + kr) * Nn + bn * 64 + c4]);
        }
        __syncthreads();
#pragma unroll
        for (int k = 0; k < 32; ++k) {
            float a[4];
#pragma unroll
            for (int i = 0; i < 4; ++i) a[i] = As[ty * 4 + i][k];
            float4 bv = *reinterpret_cast<const float4*>(&Bs[k][tx * 4]);
            float b[4] = {bv.x, bv.y, bv.z, bv.w};
#pragma unroll
            for (int i = 0; i < 4; ++i)
#pragma unroll
                for (int j = 0; j < 4; ++j) acc[i][j] = fmaf(a[i], b[j], acc[i][j]);
        }
    }

#pragma unroll
    for (int i = 0; i < 4; ++i) {
        int row = bm * 64 + ty * 4 + i;
        if (row < M) {
            float4 v = {acc[i][0], acc[i][1], acc[i][2], acc[i][3]};
            *reinterpret_cast<float4*>(&C[(size_t)row * Nn + bn * 64 + tx * 4]) = v;
        }
    }
}

// ---------------------------------------------------------------------------
// Kernel 2: per relation r, head h, edge tile of 64:
//   k_tile = x[src] @ WK[r][:, h*128 : h*128+128]   (gathered GEMM, K=128)
//   score[e,h] = dot(k_tile[e,:], q[dst[e], h*128:...]) * SCALE
//   numer = relu(score)^2 + EPS ; atomicAdd denom[dst,h]
// ---------------------------------------------------------------------------
__global__ __launch_bounds__(256) void scores_kernel(const float* __restrict__ x,
                                                     const float* __restrict__ WK,
                                                     const float* __restrict__ q,
                                                     const int* __restrict__ src,
                                                     const int* __restrict__ dst,
                                                     float* __restrict__ numer,
                                                     float* __restrict__ denom)
{
    __shared__ float As[64][36];    // gathered x rows [edge][k]
    __shared__ float Bs[32][128];   // WK chunk [k][col]
    __shared__ float red[64][16];   // per-edge partial reduction

    const int tid = threadIdx.x;
    const int bm = blockIdx.x;          // edge tile
    const int h  = blockIdx.y;          // head
    const int r  = blockIdx.z;          // relation
    const int hofs = h * DIM;

    const float* Wr   = WK + (size_t)r * DIM * HDIM;
    const int*   srcr = src + r * NEDGE;
    const int*   dstr = dst + r * NEDGE;

    const int ty = tid >> 4, tx = tid & 15;

    int arow[2];
#pragma unroll
    for (int p = 0; p < 2; ++p) {
        int e = bm * 64 + p * 32 + (tid >> 3);
        e = (e < NEDGE) ? e : (NEDGE - 1);
        arow[p] = srcr[e];
    }

    float acc[4][8] = {};

    for (int kk = 0; kk < DIM; kk += 32) {
        __syncthreads();
#pragma unroll
        for (int p = 0; p < 2; ++p) {
            int row = p * 32 + (tid >> 3);
            int k4  = (tid & 7) * 4;
            float4 v = *reinterpret_cast<const float4*>(&x[(size_t)arow[p] * DIM + kk + k4]);
            *reinterpret_cast<float4*>(&As[row][k4]) = v;
        }
#pragma unroll
        for (int p = 0; p < 4; ++p) {
            int kr = p * 8 + (tid >> 5);
            int c4 = (tid & 31) * 4;
            *reinterpret_cast<float4*>(&Bs[kr][c4]) =
                *reinterpret_cast<const float4*>(&Wr[(size_t)(kk + kr) * HDIM + hofs + c4]);
        }
        __syncthreads();
#pragma unroll
        for (int k = 0; k < 32; ++k) {
            float a[4];
#pragma unroll
            for (int i = 0; i < 4; ++i) a[i] = As[ty * 4 + i][k];
            float4 b0 = *reinterpret_cast<const float4*>(&Bs[k][tx * 8]);
            float4 b1 = *reinterpret_cast<const float4*>(&Bs[k][tx * 8 + 4]);
            float b[8] = {b0.x, b0.y, b0.z, b0.w, b1.x, b1.y, b1.z, b1.w};
#pragma unroll
            for (int i = 0; i < 4; ++i)
#pragma unroll
                for (int j = 0; j < 8; ++j) acc[i][j] = fmaf(a[i], b[j], acc[i][j]);
        }
    }

    // dot k-fragment with q[dst]
#pragma unroll
    for (int i = 0; i < 4; ++i) {
        int e  = bm * 64 + ty * 4 + i;
        int ec = (e < NEDGE) ? e : (NEDGE - 1);
        int de = dstr[ec];
        const float* qrow = q + (size_t)de * HDIM + hofs + tx * 8;
        float4 q0 = *reinterpret_cast<const float4*>(qrow);
        float4 q1 = *reinterpret_cast<const float4*>(qrow + 4);
        float p = acc[i][0] * q0.x + acc[i][1] * q0.y + acc[i][2] * q0.z + acc[i][3] * q0.w
                + acc[i][4] * q1.x + acc[i][5] * q1.y + acc[i][6] * q1.z + acc[i][7] * q1.w;
        red[ty * 4 + i][tx] = p;
    }
    __syncthreads();

    if (tid < 64) {
        int e = bm * 64 + tid;
        if (e < NEDGE) {
            float s = 0.f;
#pragma unroll
            for (int j = 0; j < 16; ++j) s += red[tid][j];
            s *= SCALE;
            float m  = fmaxf(s, 0.f);
            float nu = m * m + EPS_F;
            numer[(size_t)(r * NEDGE + e) * HEADS + h] = nu;
            int de = dstr[e];
            atomicAdd(&denom[de * HEADS + h], nu);
        }
    }
}

// ---------------------------------------------------------------------------
// Kernel 3: per relation r, head h, edge tile of 64:
//   v_tile = x[src] @ WV[r][:, h*128:...]
//   z[dst, h*128 + c] += v_tile[e,c] * numer[e,h] / denom[dst,h]
// ---------------------------------------------------------------------------
__global__ __launch_bounds__(256) void scatter_kernel(const float* __restrict__ x,
                                                      const float* __restrict__ WV,
                                                      const float* __restrict__ numer,
                                                      const float* __restrict__ denom,
                                                      const int* __restrict__ src,
                                                      const int* __restrict__ dst,
                                                      float* __restrict__ z)
{
    __shared__ float As[64][36];
    __shared__ float Bs[32][128];

    const int tid = threadIdx.x;
    const int bm = blockIdx.x;
    const int h  = blockIdx.y;
    const int r  = blockIdx.z;
    const int hofs = h * DIM;

    const float* Wr   = WV + (size_t)r * DIM * HDIM;
    const int*   srcr = src + r * NEDGE;
    const int*   dstr = dst + r * NEDGE;

    const int ty = tid >> 4, tx = tid & 15;

    int arow[2];
#pragma unroll
    for (int p = 0; p < 2; ++p) {
        int e = bm * 64 + p * 32 + (tid >> 3);
        e = (e < NEDGE) ? e : (NEDGE - 1);
        arow[p] = srcr[e];
    }

    float acc[4][8] = {};

    for (int kk = 0; kk < DIM; kk += 32) {
        __syncthreads();
#pragma unroll
        for (int p = 0; p < 2; ++p) {
            int row = p * 32 + (tid >> 3);
            int k4  = (tid & 7) * 4;
            float4 v = *reinterpret_cast<const float4*>(&x[(size_t)arow[p] * DIM + kk + k4]);
            *reinterpret_cast<float4*>(&As[row][k4]) = v;
        }
#pragma unroll
        for (int p = 0; p < 4; ++p) {
            int kr = p * 8 + (tid >> 5);
            int c4 = (tid & 31) * 4;
            *reinterpret_cast<float4*>(&Bs[kr][c4]) =
                *reinterpret_cast<const float4*>(&Wr[(size_t)(kk + kr) * HDIM + hofs + c4]);
        }
        __syncthreads();
#pragma unroll
        for (int k = 0; k < 32; ++k) {
            float a[4];
#pragma unroll
            for (int i = 0; i < 4; ++i) a[i] = As[ty * 4 + i][k];
            float4 b0 = *reinterpret_cast<const float4*>(&Bs[k][tx * 8]);
            float4 b1 = *reinterpret_cast<const float4*>(&Bs[k][tx * 8 + 4]);
            float b[8] = {b0.x, b0.y, b0.z, b0.w, b1.x, b1.y, b1.z, b1.w};
#pragma unroll
            for (int i = 0; i < 4; ++i)
#pragma unroll
                for (int j = 0; j < 8; ++j) acc[i][j] = fmaf(a[i], b[j], acc[i][j]);
        }
    }

#pragma unroll
    for (int i = 0; i < 4; ++i) {
        int e = bm * 64 + ty * 4 + i;
        if (e < NEDGE) {
            int de = dstr[e];
            float nu  = numer[(size_t)(r * NEDGE + e) * HEADS + h];
            float dn  = denom[de * HEADS + h];
            float nrm = nu / dn;
            float* zrow = z + (size_t)de * HDIM + hofs + tx * 8;
#pragma unroll
            for (int j = 0; j < 8; ++j) atomicAdd(&zrow[j], acc[i][j] * nrm);
        }
    }
}

// ---------------------------------------------------------------------------
extern "C" void kernel_launch(void* const* d_in, const int* in_sizes, int n_in,
                              void* d_out, int out_size, void* d_ws, size_t ws_size,
                              hipStream_t stream)
{
    const float* x   = (const float*)d_in[0];
    const float* WQ  = (const float*)d_in[1];
    const float* WK  = (const float*)d_in[2];
    const float* WV  = (const float*)d_in[3];
    const float* WO  = (const float*)d_in[4];
    const int*   src = (const int*)d_in[5];
    const int*   dst = (const int*)d_in[6];
    float* out = (float*)d_out;

    float* ws    = (float*)d_ws;
    float* q     = ws;                                   // 50000*512 = 25,600,000
    float* numer = ws + (size_t)25600000;                // 150000*4  =    600,000
    float* denom = ws + (size_t)26200000;                // 50000*4   =    200,000
    float* z     = ws + (size_t)26400000;                // 50000*512 = 25,600,000

    hipMemsetAsync(denom, 0, (size_t)N_NODES * HEADS * sizeof(float), stream);
    hipMemsetAsync(z,     0, (size_t)N_NODES * HDIM  * sizeof(float), stream);

    dim3 blk(256);
    const int MT = (N_NODES + 63) / 64;   // 782

    // q = x @ WQ   [50000,128]x[128,512]
    gemm_f32<<<dim3(MT, HDIM / 64), blk, 0, stream>>>(x, WQ, q, N_NODES, HDIM, DIM);

    // scores -> numer, denom
    scores_kernel<<<dim3((NEDGE + 63) / 64, HEADS, NREL), blk, 0, stream>>>(
        x, WK, q, src, dst, numer, denom);

    // v, normalize, scatter into z
    scatter_kernel<<<dim3((NEDGE + 63) / 64, HEADS, NREL), blk, 0, stream>>>(
        x, WV, numer, denom, src, dst, z);

    // out = z @ WO  [50000,512]x[512,128]
    gemm_f32<<<dim3(MT, DIM / 64), blk, 0, stream>>>(z, WO, out, N_NODES, DIM, HDIM);
}

// Round 2
// 1100.782 us; speedup vs baseline: 2.4135x; 2.4135x over previous
//
#include <hip/hip_runtime.h>

// Problem constants (RelationalAttentionLayer)
#define N_NODES 50000
#define DIM     128
#define HEADS   4
#define HDIM    512      // HEADS * DIM
#define NREL    3
#define NEDGE   50000    // edges per relation
#define NETOT   150000   // total edges

constexpr float EPS_F  = 1e-10f;
constexpr float SCALE  = 0.044194173824159216f;  // 1/sqrt(512)

// ---------------------------------------------------------------------------
// Generic f32 GEMM: C[M,Nn] = A[M,K] @ B[K,Nn]
// 64x64 tile, BK=32, 256 threads, 4x4 per-thread tile. M may be ragged.
// ---------------------------------------------------------------------------
__global__ __launch_bounds__(256) void gemm_f32(const float* __restrict__ A,
                                                const float* __restrict__ B,
                                                float* __restrict__ C,
                                                int M, int Nn, int K)
{
    __shared__ float As[64][36];
    __shared__ float Bs[32][64];

    const int tid = threadIdx.x;
    const int bm = blockIdx.x, bn = blockIdx.y;
    const int ty = tid >> 4, tx = tid & 15;

    int arow[2];
#pragma unroll
    for (int p = 0; p < 2; ++p) {
        int r = bm * 64 + p * 32 + (tid >> 3);
        arow[p] = (r < M) ? r : (M - 1);
    }

    float acc[4][4] = {};

    for (int kk = 0; kk < K; kk += 32) {
        __syncthreads();
#pragma unroll
        for (int p = 0; p < 2; ++p) {
            int row = p * 32 + (tid >> 3);
            int k4  = (tid & 7) * 4;
            float4 v = *reinterpret_cast<const float4*>(&A[(size_t)arow[p] * K + kk + k4]);
            *reinterpret_cast<float4*>(&As[row][k4]) = v;
        }
#pragma unroll
        for (int p = 0; p < 2; ++p) {
            int kr = p * 16 + (tid >> 4);
            int c4 = (tid & 15) * 4;
            *reinterpret_cast<float4*>(&Bs[kr][c4]) =
                *reinterpret_cast<const float4*>(&B[(size_t)(kk + kr) * Nn + bn * 64 + c4]);
        }
        __syncthreads();
#pragma unroll
        for (int k = 0; k < 32; ++k) {
            float a[4];
#pragma unroll
            for (int i = 0; i < 4; ++i) a[i] = As[ty * 4 + i][k];
            float4 bv = *reinterpret_cast<const float4*>(&Bs[k][tx * 4]);
            float b[4] = {bv.x, bv.y, bv.z, bv.w};
#pragma unroll
            for (int i = 0; i < 4; ++i)
#pragma unroll
                for (int j = 0; j < 4; ++j) acc[i][j] = fmaf(a[i], b[j], acc[i][j]);
        }
    }

#pragma unroll
    for (int i = 0; i < 4; ++i) {
        int row = bm * 64 + ty * 4 + i;
        if (row < M) {
            float4 v = {acc[i][0], acc[i][1], acc[i][2], acc[i][3]};
            *reinterpret_cast<float4*>(&C[(size_t)row * Nn + bn * 64 + tx * 4]) = v;
        }
    }
}

// ---------------------------------------------------------------------------
// Kernel 2: per relation r, head h, edge tile of 64:
//   k_tile = x[src] @ WK[r][:, h*128:...]; score = dot(k_tile, q[dst]) * SCALE
//   numer = relu(score)^2 + EPS ; atomicAdd denom[dst,h]  (only 600K atomics)
// ---------------------------------------------------------------------------
__global__ __launch_bounds__(256) void scores_kernel(const float* __restrict__ x,
                                                     const float* __restrict__ WK,
                                                     const float* __restrict__ q,
                                                     const int* __restrict__ src,
                                                     const int* __restrict__ dst,
                                                     float* __restrict__ numer,
                                                     float* __restrict__ denom)
{
    __shared__ float As[64][36];
    __shared__ float Bs[32][128];
    __shared__ float red[64][16];

    const int tid = threadIdx.x;
    const int bm = blockIdx.x;
    const int h  = blockIdx.y;
    const int r  = blockIdx.z;
    const int hofs = h * DIM;

    const float* Wr   = WK + (size_t)r * DIM * HDIM;
    const int*   srcr = src + r * NEDGE;
    const int*   dstr = dst + r * NEDGE;

    const int ty = tid >> 4, tx = tid & 15;

    int arow[2];
#pragma unroll
    for (int p = 0; p < 2; ++p) {
        int e = bm * 64 + p * 32 + (tid >> 3);
        e = (e < NEDGE) ? e : (NEDGE - 1);
        arow[p] = srcr[e];
    }

    float acc[4][8] = {};

    for (int kk = 0; kk < DIM; kk += 32) {
        __syncthreads();
#pragma unroll
        for (int p = 0; p < 2; ++p) {
            int row = p * 32 + (tid >> 3);
            int k4  = (tid & 7) * 4;
            float4 v = *reinterpret_cast<const float4*>(&x[(size_t)arow[p] * DIM + kk + k4]);
            *reinterpret_cast<float4*>(&As[row][k4]) = v;
        }
#pragma unroll
        for (int p = 0; p < 4; ++p) {
            int kr = p * 8 + (tid >> 5);
            int c4 = (tid & 31) * 4;
            *reinterpret_cast<float4*>(&Bs[kr][c4]) =
                *reinterpret_cast<const float4*>(&Wr[(size_t)(kk + kr) * HDIM + hofs + c4]);
        }
        __syncthreads();
#pragma unroll
        for (int k = 0; k < 32; ++k) {
            float a[4];
#pragma unroll
            for (int i = 0; i < 4; ++i) a[i] = As[ty * 4 + i][k];
            float4 b0 = *reinterpret_cast<const float4*>(&Bs[k][tx * 8]);
            float4 b1 = *reinterpret_cast<const float4*>(&Bs[k][tx * 8 + 4]);
            float b[8] = {b0.x, b0.y, b0.z, b0.w, b1.x, b1.y, b1.z, b1.w};
#pragma unroll
            for (int i = 0; i < 4; ++i)
#pragma unroll
                for (int j = 0; j < 8; ++j) acc[i][j] = fmaf(a[i], b[j], acc[i][j]);
        }
    }

#pragma unroll
    for (int i = 0; i < 4; ++i) {
        int e  = bm * 64 + ty * 4 + i;
        int ec = (e < NEDGE) ? e : (NEDGE - 1);
        int de = dstr[ec];
        const float* qrow = q + (size_t)de * HDIM + hofs + tx * 8;
        float4 q0 = *reinterpret_cast<const float4*>(qrow);
        float4 q1 = *reinterpret_cast<const float4*>(qrow + 4);
        float p = acc[i][0] * q0.x + acc[i][1] * q0.y + acc[i][2] * q0.z + acc[i][3] * q0.w
                + acc[i][4] * q1.x + acc[i][5] * q1.y + acc[i][6] * q1.z + acc[i][7] * q1.w;
        red[ty * 4 + i][tx] = p;
    }
    __syncthreads();

    if (tid < 64) {
        int e = bm * 64 + tid;
        if (e < NEDGE) {
            float s = 0.f;
#pragma unroll
            for (int j = 0; j < 16; ++j) s += red[tid][j];
            s *= SCALE;
            float m  = fmaxf(s, 0.f);
            float nu = m * m + EPS_F;
            numer[(size_t)(r * NEDGE + e) * HEADS + h] = nu;
            int de = dstr[e];
            atomicAdd(&denom[de * HEADS + h], nu);
        }
    }
}

// ---------------------------------------------------------------------------
// CSR build: count -> scan -> fill (edges sorted by dst, global edge ids)
// ---------------------------------------------------------------------------
__global__ __launch_bounds__(256) void csr_count(const int* __restrict__ dst, int* __restrict__ cnt)
{
    int e = blockIdx.x * 256 + threadIdx.x;
    if (e < NETOT) atomicAdd(&cnt[dst[e]], 1);
}

__global__ __launch_bounds__(1024) void csr_scan(const int* __restrict__ cnt,
                                                 int* __restrict__ row_ptr,
                                                 int* __restrict__ cursor)
{
    __shared__ int part[1024];
    const int t = threadIdx.x;
    const int per = (N_NODES + 1023) / 1024;   // 49
    int b0 = t * per;
    int b1 = b0 + per; if (b1 > N_NODES) b1 = N_NODES;
    if (b0 > N_NODES) b0 = N_NODES;

    int s = 0;
    for (int i = b0; i < b1; ++i) s += cnt[i];
    part[t] = s;
    __syncthreads();
    for (int off = 1; off < 1024; off <<= 1) {
        int v = (t >= off) ? part[t - off] : 0;
        __syncthreads();
        part[t] += v;
        __syncthreads();
    }
    int run = (t == 0) ? 0 : part[t - 1];
    for (int i = b0; i < b1; ++i) {
        row_ptr[i] = run;
        cursor[i]  = run;
        run += cnt[i];
    }
    if (t == 1023) row_ptr[N_NODES] = run;
}

__global__ __launch_bounds__(256) void csr_fill(const int* __restrict__ dst,
                                                int* __restrict__ cursor,
                                                int* __restrict__ eids)
{
    int e = blockIdx.x * 256 + threadIdx.x;
    if (e < NETOT) {
        int pos = atomicAdd(&cursor[dst[e]], 1);
        eids[pos] = e;
    }
}

// ---------------------------------------------------------------------------
// Aggregation (atomic-free): one wave per node.
//   y_h[n, r*128 + d] = sum_{e -> n, rel r} (numer[e,h]/denom[n,h]) * x[src_e, d]
// ---------------------------------------------------------------------------
__global__ __launch_bounds__(256) void agg_kernel(const float* __restrict__ x,
                                                  const float* __restrict__ numer,
                                                  const float* __restrict__ denom,
                                                  const int* __restrict__ row_ptr,
                                                  const int* __restrict__ eids,
                                                  const int* __restrict__ src,
                                                  float* __restrict__ y, int h)
{
    const int wave = threadIdx.x >> 6, lane = threadIdx.x & 63;
    const int n = blockIdx.x * 4 + wave;
    if (n >= N_NODES) return;

    const int beg = row_ptr[n], end = row_ptr[n + 1];
    float a00 = 0.f, a01 = 0.f, a10 = 0.f, a11 = 0.f, a20 = 0.f, a21 = 0.f;

    if (beg < end) {
        const float dinv = 1.0f / denom[n * HEADS + h];
        for (int i = beg; i < end; ++i) {
            int e = eids[i];
            int s = src[e];
            float w  = numer[(size_t)e * HEADS + h] * dinv;
            float x0 = x[(size_t)s * DIM + lane];
            float x1 = x[(size_t)s * DIM + 64 + lane];
            int r = e / NEDGE;   // wave-uniform
            if (r == 0)      { a00 = fmaf(w, x0, a00); a01 = fmaf(w, x1, a01); }
            else if (r == 1) { a10 = fmaf(w, x0, a10); a11 = fmaf(w, x1, a11); }
            else             { a20 = fmaf(w, x0, a20); a21 = fmaf(w, x1, a21); }
        }
    }
    float* yr = y + (size_t)n * (NREL * DIM);
    yr[lane]        = a00;  yr[64 + lane]  = a01;
    yr[128 + lane]  = a10;  yr[192 + lane] = a11;
    yr[256 + lane]  = a20;  yr[320 + lane] = a21;
}

// ---------------------------------------------------------------------------
// z-GEMM per head: z[:, h*128+c] = y_h[N,384] @ Bv, Bv[r*128+d][c] = WV[r][d][h*128+c]
// 64x128 tile, BK=32, acc[4][8].
// ---------------------------------------------------------------------------
__global__ __launch_bounds__(256) void zgemm_kernel(const float* __restrict__ y,
                                                    const float* __restrict__ WV,
                                                    float* __restrict__ z, int h)
{
    __shared__ float As[64][36];
    __shared__ float Bs[32][128];

    const int tid = threadIdx.x;
    const int bm = blockIdx.x;
    const int ty = tid >> 4, tx = tid & 15;
    const int KK = NREL * DIM;   // 384

    int arow[2];
#pragma unroll
    for (int p = 0; p < 2; ++p) {
        int r = bm * 64 + p * 32 + (tid >> 3);
        arow[p] = (r < N_NODES) ? r : (N_NODES - 1);
    }

    float acc[4][8] = {};

    for (int kk = 0; kk < KK; kk += 32) {
        __syncthreads();
#pragma unroll
        for (int p = 0; p < 2; ++p) {
            int row = p * 32 + (tid >> 3);
            int k4  = (tid & 7) * 4;
            float4 v = *reinterpret_cast<const float4*>(&y[(size_t)arow[p] * KK + kk + k4]);
            *reinterpret_cast<float4*>(&As[row][k4]) = v;
        }
#pragma unroll
        for (int p = 0; p < 4; ++p) {
            int kr = p * 8 + (tid >> 5);
            int k  = kk + kr;
            int r  = k >> 7;      // which relation
            int d  = k & 127;
            int c4 = (tid & 31) * 4;
            *reinterpret_cast<float4*>(&Bs[kr][c4]) =
                *reinterpret_cast<const float4*>(&WV[(size_t)r * DIM * HDIM + (size_t)d * HDIM + h * DIM + c4]);
        }
        __syncthreads();
#pragma unroll
        for (int k = 0; k < 32; ++k) {
            float a[4];
#pragma unroll
            for (int i = 0; i < 4; ++i) a[i] = As[ty * 4 + i][k];
            float4 b0 = *reinterpret_cast<const float4*>(&Bs[k][tx * 8]);
            float4 b1 = *reinterpret_cast<const float4*>(&Bs[k][tx * 8 + 4]);
            float b[8] = {b0.x, b0.y, b0.z, b0.w, b1.x, b1.y, b1.z, b1.w};
#pragma unroll
            for (int i = 0; i < 4; ++i)
#pragma unroll
                for (int j = 0; j < 8; ++j) acc[i][j] = fmaf(a[i], b[j], acc[i][j]);
        }
    }

#pragma unroll
    for (int i = 0; i < 4; ++i) {
        int row = bm * 64 + ty * 4 + i;
        if (row < N_NODES) {
            float* zr = z + (size_t)row * HDIM + h * DIM + tx * 8;
            float4 v0 = {acc[i][0], acc[i][1], acc[i][2], acc[i][3]};
            float4 v1 = {acc[i][4], acc[i][5], acc[i][6], acc[i][7]};
            *reinterpret_cast<float4*>(zr)     = v0;
            *reinterpret_cast<float4*>(zr + 4) = v1;
        }
    }
}

// ---------------------------------------------------------------------------
extern "C" void kernel_launch(void* const* d_in, const int* in_sizes, int n_in,
                              void* d_out, int out_size, void* d_ws, size_t ws_size,
                              hipStream_t stream)
{
    const float* x   = (const float*)d_in[0];
    const float* WQ  = (const float*)d_in[1];
    const float* WK  = (const float*)d_in[2];
    const float* WV  = (const float*)d_in[3];
    const float* WO  = (const float*)d_in[4];
    const int*   src = (const int*)d_in[5];
    const int*   dst = (const int*)d_in[6];
    float* out = (float*)d_out;

    float* ws = (float*)d_ws;
    // layout (floats):
    float* q_z   = ws;                        // 25,600,000  (q, later z)
    float* y_h   = ws + 25600000;             // 19,200,000  (per-head y)
    float* numer = ws + 44800000;             //    600,000
    float* denom = ws + 45400000;             //    200,000
    int*   iws     = (int*)(ws + 45600000);
    int*   cnt     = iws;                     //  50,000
    int*   row_ptr = iws + 50000;             //  50,001
    int*   cursor  = iws + 100001;            //  50,000
    int*   eids    = iws + 150001;            // 150,000
    // total ~183.6 MB

    hipMemsetAsync(cnt,   0, (size_t)N_NODES * sizeof(int), stream);
    hipMemsetAsync(denom, 0, (size_t)N_NODES * HEADS * sizeof(float), stream);

    dim3 blk(256);
    const int MT = (N_NODES + 63) / 64;   // 782

    // q = x @ WQ
    gemm_f32<<<dim3(MT, HDIM / 64), blk, 0, stream>>>(x, WQ, q_z, N_NODES, HDIM, DIM);

    // scores -> numer, denom
    scores_kernel<<<dim3((NEDGE + 63) / 64, HEADS, NREL), blk, 0, stream>>>(
        x, WK, q_z, src, dst, numer, denom);

    // CSR build (by dst over all 150K edges)
    csr_count<<<dim3((NETOT + 255) / 256), blk, 0, stream>>>(dst, cnt);
    csr_scan<<<dim3(1), dim3(1024), 0, stream>>>(cnt, row_ptr, cursor);
    csr_fill<<<dim3((NETOT + 255) / 256), blk, 0, stream>>>(dst, cursor, eids);

    // per-head: atomic-free weighted aggregation, then dense GEMM into z
    // (z overlays q, which is dead after scores_kernel)
    for (int h = 0; h < HEADS; ++h) {
        agg_kernel<<<dim3((N_NODES + 3) / 4), blk, 0, stream>>>(
            x, numer, denom, row_ptr, eids, src, y_h, h);
        zgemm_kernel<<<dim3(MT), blk, 0, stream>>>(y_h, WV, q_z, h);
    }

    // out = z @ WO
    gemm_f32<<<dim3(MT, DIM / 64), blk, 0, stream>>>(q_z, WO, out, N_NODES, DIM, HDIM);
}

// Round 5
// 836.546 us; speedup vs baseline: 3.1759x; 1.3159x over previous
//
#include <hip/hip_runtime.h>
#include <stdint.h>

// Problem constants (RelationalAttentionLayer)
#define N_NODES 50000
#define DIM     128
#define HEADS   4
#define HDIM    512      // HEADS * DIM
#define NREL    3
#define NEDGE   50000    // edges per relation
#define NETOT   150000   // total edges
#define FLAG_CAP 32768

constexpr float EPS_F  = 1e-10f;
constexpr float SCALE  = 0.044194173824159216f;  // 1/sqrt(512)
constexpr float TAU    = 0.005f;                 // exact-repair band

typedef unsigned short ushort_t;
typedef __attribute__((ext_vector_type(8))) short  short8;
typedef __attribute__((ext_vector_type(4))) unsigned short ushort4v;
typedef __attribute__((ext_vector_type(4))) float  f32x4;

__device__ __forceinline__ float b2f(ushort_t u) {
    unsigned int v = ((unsigned int)u) << 16;
    float f; __builtin_memcpy(&f, &v, 4); return f;
}
__device__ __forceinline__ ushort_t f2b(float f) {
    unsigned int v; __builtin_memcpy(&v, &f, 4);
    unsigned int r = v + 0x7FFFu + ((v >> 16) & 1u);   // RNE
    return (ushort_t)(r >> 16);
}

#define LDSTRIDE 40   // ushort stride per 32-elem k-row (80B, 16B slots, 2-way alias = free)

// ---------------------------------------------------------------------------
// bf16 MFMA GEMM (single precision): C[M,N] = A[M,K] @ Bt[N][K]^T
// 128x128 tile, BK=32, 4 waves (2x2). Used for zgemm (v path) and out gemm.
// ---------------------------------------------------------------------------
template <int OUTMODE>   // 0 = f32 store, 1 = bf16 store
__global__ __launch_bounds__(256) void gemm_mfma(const ushort_t* __restrict__ A,
                                                 const ushort_t* __restrict__ Bt,
                                                 void* __restrict__ Cv,
                                                 int M, int K, int ldc)
{
    __shared__ ushort_t As[128 * LDSTRIDE];
    __shared__ ushort_t Bs[128 * LDSTRIDE];

    const int tid = threadIdx.x;
    const int w = tid >> 6, l = tid & 63;
    const int bm = blockIdx.x, bn = blockIdx.y;
    const int wr = w >> 1, wc = w & 1;

    int s_ro[2]; size_t s_ao[2], s_bo[2];
#pragma unroll
    for (int i = 0; i < 2; ++i) {
        int c = tid + 256 * i;
        int row = c >> 2, slot = c & 3;
        s_ro[i] = row * LDSTRIDE + slot * 8;
        int grow = bm * 128 + row; if (grow >= M) grow = M - 1;
        s_ao[i] = (size_t)grow * K + slot * 8;
        s_bo[i] = (size_t)(bn * 128 + row) * K + slot * 8;
    }

    int a_off[4], b_off[4];
#pragma unroll
    for (int mi = 0; mi < 4; ++mi)
        a_off[mi] = (wr * 64 + mi * 16 + (l & 15)) * LDSTRIDE + (l >> 4) * 8;
#pragma unroll
    for (int ni = 0; ni < 4; ++ni)
        b_off[ni] = (wc * 64 + ni * 16 + (l & 15)) * LDSTRIDE + (l >> 4) * 8;

    f32x4 acc[4][4] = {};

    for (int kk = 0; kk < K; kk += 32) {
        __syncthreads();
#pragma unroll
        for (int i = 0; i < 2; ++i) {
            *(short8*)&As[s_ro[i]] = *(const short8*)(A  + s_ao[i] + kk);
            *(short8*)&Bs[s_ro[i]] = *(const short8*)(Bt + s_bo[i] + kk);
        }
        __syncthreads();

        short8 af[4], bfr[4];
#pragma unroll
        for (int mi = 0; mi < 4; ++mi) af[mi]  = *(const short8*)&As[a_off[mi]];
#pragma unroll
        for (int ni = 0; ni < 4; ++ni) bfr[ni] = *(const short8*)&Bs[b_off[ni]];

#pragma unroll
        for (int mi = 0; mi < 4; ++mi)
#pragma unroll
            for (int ni = 0; ni < 4; ++ni)
                acc[mi][ni] = __builtin_amdgcn_mfma_f32_16x16x32_bf16(af[mi], bfr[ni], acc[mi][ni], 0, 0, 0);
    }

#pragma unroll
    for (int mi = 0; mi < 4; ++mi)
#pragma unroll
        for (int j = 0; j < 4; ++j) {
            int row = bm * 128 + wr * 64 + mi * 16 + (l >> 4) * 4 + j;
            if (row < M) {
#pragma unroll
                for (int ni = 0; ni < 4; ++ni) {
                    int col = bn * 128 + wc * 64 + ni * 16 + (l & 15);
                    if (OUTMODE == 1)
                        ((ushort_t*)Cv)[(size_t)row * ldc + col] = f2b(acc[mi][ni][j]);
                    else
                        ((float*)Cv)[(size_t)row * ldc + col] = acc[mi][ni][j];
                }
            }
        }
}

// ---------------------------------------------------------------------------
// Split-bf16 dense GEMM (3-term, near-f32): C = (Ah+Al)[M,128] @ (Bh+Bl)t[512][128]
// f32 out, ldc=512. Used for q = x @ WQ.
// ---------------------------------------------------------------------------
__global__ __launch_bounds__(256) void gemm_split(const ushort_t* __restrict__ Ahg,
                                                  const ushort_t* __restrict__ Alg,
                                                  const ushort_t* __restrict__ Bhg,
                                                  const ushort_t* __restrict__ Blg,
                                                  float* __restrict__ C, int M)
{
    __shared__ ushort_t Ah[128 * LDSTRIDE], Al[128 * LDSTRIDE];
    __shared__ ushort_t Bh[128 * LDSTRIDE], Bl[128 * LDSTRIDE];

    const int tid = threadIdx.x;
    const int w = tid >> 6, l = tid & 63;
    const int bm = blockIdx.x, bn = blockIdx.y;
    const int wr = w >> 1, wc = w & 1;

    int s_ro[2]; size_t s_ao[2], s_bo[2];
#pragma unroll
    for (int i = 0; i < 2; ++i) {
        int c = tid + 256 * i;
        int row = c >> 2, slot = c & 3;
        s_ro[i] = row * LDSTRIDE + slot * 8;
        int grow = bm * 128 + row; if (grow >= M) grow = M - 1;
        s_ao[i] = (size_t)grow * 128 + slot * 8;
        s_bo[i] = (size_t)(bn * 128 + row) * 128 + slot * 8;
    }

    int a_off[4], b_off[4];
#pragma unroll
    for (int mi = 0; mi < 4; ++mi)
        a_off[mi] = (wr * 64 + mi * 16 + (l & 15)) * LDSTRIDE + (l >> 4) * 8;
#pragma unroll
    for (int ni = 0; ni < 4; ++ni)
        b_off[ni] = (wc * 64 + ni * 16 + (l & 15)) * LDSTRIDE + (l >> 4) * 8;

    f32x4 acc[4][4] = {};

    for (int kk = 0; kk < 128; kk += 32) {
        __syncthreads();
#pragma unroll
        for (int i = 0; i < 2; ++i) {
            *(short8*)&Ah[s_ro[i]] = *(const short8*)(Ahg + s_ao[i] + kk);
            *(short8*)&Al[s_ro[i]] = *(const short8*)(Alg + s_ao[i] + kk);
            *(short8*)&Bh[s_ro[i]] = *(const short8*)(Bhg + s_bo[i] + kk);
            *(short8*)&Bl[s_ro[i]] = *(const short8*)(Blg + s_bo[i] + kk);
        }
        __syncthreads();

        short8 ah[4], al[4], bh[4], bl[4];
#pragma unroll
        for (int mi = 0; mi < 4; ++mi) { ah[mi] = *(const short8*)&Ah[a_off[mi]];
                                         al[mi] = *(const short8*)&Al[a_off[mi]]; }
#pragma unroll
        for (int ni = 0; ni < 4; ++ni) { bh[ni] = *(const short8*)&Bh[b_off[ni]];
                                         bl[ni] = *(const short8*)&Bl[b_off[ni]]; }

#pragma unroll
        for (int mi = 0; mi < 4; ++mi)
#pragma unroll
            for (int ni = 0; ni < 4; ++ni) {
                acc[mi][ni] = __builtin_amdgcn_mfma_f32_16x16x32_bf16(ah[mi], bh[ni], acc[mi][ni], 0, 0, 0);
                acc[mi][ni] = __builtin_amdgcn_mfma_f32_16x16x32_bf16(ah[mi], bl[ni], acc[mi][ni], 0, 0, 0);
                acc[mi][ni] = __builtin_amdgcn_mfma_f32_16x16x32_bf16(al[mi], bh[ni], acc[mi][ni], 0, 0, 0);
            }
    }

#pragma unroll
    for (int mi = 0; mi < 4; ++mi)
#pragma unroll
        for (int j = 0; j < 4; ++j) {
            int row = bm * 128 + wr * 64 + mi * 16 + (l >> 4) * 4 + j;
            if (row < M) {
#pragma unroll
                for (int ni = 0; ni < 4; ++ni) {
                    int col = bn * 128 + wc * 64 + ni * 16 + (l & 15);
                    C[(size_t)row * 512 + col] = acc[mi][ni][j];
                }
            }
        }
}

// ---------------------------------------------------------------------------
// Fused scores: per relation, edge tile of 128:
//   k = (x_hi+x_lo)[src] @ (W_hi+W_lo)  (3-term split MFMA, per head n-chunk)
//   s[e,h] = SCALE * dot(k[e, h*128:...], q_f32[dst, h*128:...])
// writes RAW scores; flags |s|<TAU pairs for exact repair.
// ---------------------------------------------------------------------------
__global__ __launch_bounds__(256) void scores_fused(const ushort_t* __restrict__ xh,
                                                    const ushort_t* __restrict__ xl,
                                                    const ushort_t* __restrict__ Wh,
                                                    const ushort_t* __restrict__ Wl,
                                                    const float* __restrict__ q,
                                                    const int* __restrict__ srcr,
                                                    const int* __restrict__ dstr,
                                                    float* __restrict__ sc_out,
                                                    int rel,
                                                    int* __restrict__ flagcnt,
                                                    int* __restrict__ fids)
{
    __shared__ ushort_t Ah[128 * LDSTRIDE], Al[128 * LDSTRIDE];
    __shared__ ushort_t Bh[128 * LDSTRIDE], Bl[128 * LDSTRIDE];
    __shared__ float sc_red[128][2];

    const int tid = threadIdx.x;
    const int w = tid >> 6, l = tid & 63;
    const int bm = blockIdx.x;
    const int wr = w >> 1, wc = w & 1;

    int s_ro[2], s_row[2], s_slot[2], s_arow[2];
#pragma unroll
    for (int i = 0; i < 2; ++i) {
        int c = tid + 256 * i;
        s_row[i] = c >> 2; s_slot[i] = c & 3;
        s_ro[i] = s_row[i] * LDSTRIDE + s_slot[i] * 8;
        int e = bm * 128 + s_row[i]; if (e >= NEDGE) e = NEDGE - 1;
        s_arow[i] = srcr[e];
    }

    int a_off[4], b_off[4];
#pragma unroll
    for (int mi = 0; mi < 4; ++mi)
        a_off[mi] = (wr * 64 + mi * 16 + (l & 15)) * LDSTRIDE + (l >> 4) * 8;
#pragma unroll
    for (int ni = 0; ni < 4; ++ni)
        b_off[ni] = (wc * 64 + ni * 16 + (l & 15)) * LDSTRIDE + (l >> 4) * 8;

    for (int nc = 0; nc < 4; ++nc) {        // n-chunk == head
        f32x4 acc[4][4] = {};
        for (int kk = 0; kk < 128; kk += 32) {
            __syncthreads();
#pragma unroll
            for (int i = 0; i < 2; ++i) {
                size_t ao = (size_t)s_arow[i] * 128 + kk + s_slot[i] * 8;
                *(short8*)&Ah[s_ro[i]] = *(const short8*)(xh + ao);
                *(short8*)&Al[s_ro[i]] = *(const short8*)(xl + ao);
                size_t bo = (size_t)(nc * 128 + s_row[i]) * 128 + kk + s_slot[i] * 8;
                *(short8*)&Bh[s_ro[i]] = *(const short8*)(Wh + bo);
                *(short8*)&Bl[s_ro[i]] = *(const short8*)(Wl + bo);
            }
            __syncthreads();

            short8 ah[4], al[4], bh[4], bl[4];
#pragma unroll
            for (int mi = 0; mi < 4; ++mi) { ah[mi] = *(const short8*)&Ah[a_off[mi]];
                                             al[mi] = *(const short8*)&Al[a_off[mi]]; }
#pragma unroll
            for (int ni = 0; ni < 4; ++ni) { bh[ni] = *(const short8*)&Bh[b_off[ni]];
                                             bl[ni] = *(const short8*)&Bl[b_off[ni]]; }
#pragma unroll
            for (int mi = 0; mi < 4; ++mi)
#pragma unroll
                for (int ni = 0; ni < 4; ++ni) {
                    acc[mi][ni] = __builtin_amdgcn_mfma_f32_16x16x32_bf16(ah[mi], bh[ni], acc[mi][ni], 0, 0, 0);
                    acc[mi][ni] = __builtin_amdgcn_mfma_f32_16x16x32_bf16(ah[mi], bl[ni], acc[mi][ni], 0, 0, 0);
                    acc[mi][ni] = __builtin_amdgcn_mfma_f32_16x16x32_bf16(al[mi], bh[ni], acc[mi][ni], 0, 0, 0);
                }
        }

        // dot k-fragments with q[dst]: frag row(edge) = (l>>4)*4+j, col = ni*16+(l&15)
#pragma unroll
        for (int mi = 0; mi < 4; ++mi)
#pragma unroll
            for (int j = 0; j < 4; ++j) {
                int e_loc = wr * 64 + mi * 16 + (l >> 4) * 4 + j;
                int e = bm * 128 + e_loc; int ec = (e < NEDGE) ? e : NEDGE - 1;
                int d = dstr[ec];
                const float* qr = q + (size_t)d * HDIM + nc * 128 + wc * 64 + (l & 15);
                float p = acc[mi][0][j] * qr[0]  + acc[mi][1][j] * qr[16]
                        + acc[mi][2][j] * qr[32] + acc[mi][3][j] * qr[48];
                p += __shfl_xor(p, 1); p += __shfl_xor(p, 2);
                p += __shfl_xor(p, 4); p += __shfl_xor(p, 8);
                if ((l & 15) == 0) sc_red[e_loc][wc] = p;
            }
        __syncthreads();

        if (tid < 128) {
            int e = bm * 128 + tid;
            if (e < NEDGE) {
                float s = (sc_red[tid][0] + sc_red[tid][1]) * SCALE;
                sc_out[(size_t)e * HEADS + nc] = s;
                if (fabsf(s) < TAU) {
                    int pos = atomicAdd(flagcnt, 1);
                    if (pos < FLAG_CAP) fids[pos] = (rel * NEDGE + e) * HEADS + nc;
                }
            }
        }
        __syncthreads();
    }
}

// ---------------------------------------------------------------------------
// Exact f32 repair of near-zero scores: one wave per flagged (edge,head) pair.
// ---------------------------------------------------------------------------
__global__ __launch_bounds__(256) void repair_kernel(const float* __restrict__ x,
                                                     const float* __restrict__ WQ,
                                                     const float* __restrict__ WK,
                                                     const int* __restrict__ src,
                                                     const int* __restrict__ dst,
                                                     const int* __restrict__ flagcnt,
                                                     const int* __restrict__ fids,
                                                     float* __restrict__ scores)
{
    int wid = blockIdx.x * 4 + (threadIdx.x >> 6);
    int l = threadIdx.x & 63;
    int nf = *flagcnt; if (nf > FLAG_CAP) nf = FLAG_CAP;
    if (wid >= nf) return;
    int p = fids[wid];
    int h = p & 3; int eg = p >> 2; int r = eg / NEDGE;
    int s = src[eg], d = dst[eg];
    const float* xs = x + (size_t)s * DIM;
    const float* xd = x + (size_t)d * DIM;
    const float* wq = WQ + h * DIM;
    const float* wk = WK + (size_t)r * DIM * HDIM + h * DIM;

    float tot = 0.f;
#pragma unroll 1
    for (int j = 0; j < 2; ++j) {
        int c = j * 64 + l;
        float qc = 0.f, kc = 0.f;
        for (int dd = 0; dd < DIM; ++dd) {
            qc = fmaf(xd[dd], wq[(size_t)dd * HDIM + c], qc);
            kc = fmaf(xs[dd], wk[(size_t)dd * HDIM + c], kc);
        }
        tot = fmaf(qc, kc, tot);
    }
    tot += __shfl_xor(tot, 1);  tot += __shfl_xor(tot, 2);
    tot += __shfl_xor(tot, 4);  tot += __shfl_xor(tot, 8);
    tot += __shfl_xor(tot, 16); tot += __shfl_xor(tot, 32);
    if (l == 0) scores[p] = tot * SCALE;
}

// ---------------------------------------------------------------------------
// numer = relu(s)^2 + eps (in place) ; atomic denom
// ---------------------------------------------------------------------------
__global__ __launch_bounds__(256) void numer_denom(float* __restrict__ scores,
                                                   const int* __restrict__ dst,
                                                   float* __restrict__ denom)
{
    int p = blockIdx.x * 256 + threadIdx.x;
    if (p < NETOT * HEADS) {
        float s = scores[p];
        float m = fmaxf(s, 0.f);
        float nu = m * m + EPS_F;
        scores[p] = nu;
        atomicAdd(&denom[dst[p >> 2] * HEADS + (p & 3)], nu);
    }
}

// ---------------------------------------------------------------------------
// prep kernels
// ---------------------------------------------------------------------------
__global__ __launch_bounds__(256) void cvt_x_split(const float* __restrict__ x,
                                                   ushort_t* __restrict__ xh,
                                                   ushort_t* __restrict__ xl)
{
    int i = (blockIdx.x * 256 + threadIdx.x) * 4;
    float4 v = *reinterpret_cast<const float4*>(x + i);
    ushort_t h0 = f2b(v.x), h1 = f2b(v.y), h2 = f2b(v.z), h3 = f2b(v.w);
    ushort4v oh = {h0, h1, h2, h3};
    ushort4v ol = {f2b(v.x - b2f(h0)), f2b(v.y - b2f(h1)),
                   f2b(v.z - b2f(h2)), f2b(v.w - b2f(h3))};
    *reinterpret_cast<ushort4v*>(xh + i) = oh;
    *reinterpret_cast<ushort4v*>(xl + i) = ol;
}

// out[C][R] bf16 = transpose(in[R][C] f32), single precision
__global__ __launch_bounds__(256) void transpose_cvt(const float* __restrict__ in,
                                                     ushort_t* __restrict__ out,
                                                     int R, int C)
{
    __shared__ float t[32][33];
    int x = threadIdx.x & 31, y0 = threadIdx.x >> 5;
    int br = blockIdx.y, bc = blockIdx.x;
#pragma unroll
    for (int k = 0; k < 4; ++k)
        t[y0 + k * 8][x] = in[(size_t)(br * 32 + y0 + k * 8) * C + bc * 32 + x];
    __syncthreads();
#pragma unroll
    for (int k = 0; k < 4; ++k) {
        int c = bc * 32 + y0 + k * 8;
        out[(size_t)c * R + br * 32 + x] = f2b(t[x][y0 + k * 8]);
    }
}

// split transpose: hi/lo pair
__global__ __launch_bounds__(256) void transpose_cvt_split(const float* __restrict__ in,
                                                           ushort_t* __restrict__ oh,
                                                           ushort_t* __restrict__ ol,
                                                           int R, int C)
{
    __shared__ float t[32][33];
    int x = threadIdx.x & 31, y0 = threadIdx.x >> 5;
    int br = blockIdx.y, bc = blockIdx.x;
#pragma unroll
    for (int k = 0; k < 4; ++k)
        t[y0 + k * 8][x] = in[(size_t)(br * 32 + y0 + k * 8) * C + bc * 32 + x];
    __syncthreads();
#pragma unroll
    for (int k = 0; k < 4; ++k) {
        int c = bc * 32 + y0 + k * 8;
        float v = t[x][y0 + k * 8];
        ushort_t hv = f2b(v);
        oh[(size_t)c * R + br * 32 + x] = hv;
        ol[(size_t)c * R + br * 32 + x] = f2b(v - b2f(hv));
    }
}

// ---------------------------------------------------------------------------
// CSR build
// ---------------------------------------------------------------------------
__global__ __launch_bounds__(256) void csr_count(const int* __restrict__ dst, int* __restrict__ cnt)
{
    int e = blockIdx.x * 256 + threadIdx.x;
    if (e < NETOT) atomicAdd(&cnt[dst[e]], 1);
}

__global__ __launch_bounds__(1024) void csr_scan(const int* __restrict__ cnt,
                                                 int* __restrict__ row_ptr,
                                                 int* __restrict__ cursor)
{
    __shared__ int part[1024];
    const int t = threadIdx.x;
    const int per = (N_NODES + 1023) / 1024;
    int b0 = t * per;
    int b1 = b0 + per; if (b1 > N_NODES) b1 = N_NODES;
    if (b0 > N_NODES) b0 = N_NODES;

    int s = 0;
    for (int i = b0; i < b1; ++i) s += cnt[i];
    part[t] = s;
    __syncthreads();
    for (int off = 1; off < 1024; off <<= 1) {
        int v = (t >= off) ? part[t - off] : 0;
        __syncthreads();
        part[t] += v;
        __syncthreads();
    }
    int run = (t == 0) ? 0 : part[t - 1];
    for (int i = b0; i < b1; ++i) {
        row_ptr[i] = run;
        cursor[i]  = run;
        run += cnt[i];
    }
    if (t == 1023) row_ptr[N_NODES] = run;
}

__global__ __launch_bounds__(256) void csr_fill(const int* __restrict__ dst,
                                                int* __restrict__ cursor,
                                                int* __restrict__ eids)
{
    int e = blockIdx.x * 256 + threadIdx.x;
    if (e < NETOT) {
        int pos = atomicAdd(&cursor[dst[e]], 1);
        eids[pos] = e;
    }
}

// ---------------------------------------------------------------------------
// agg: one wave per node (atomic-free), f32 gather of x, bf16 y write.
// ---------------------------------------------------------------------------
__global__ __launch_bounds__(256) void agg_kernel(const float* __restrict__ x,
                                                  const float* __restrict__ numer,
                                                  const float* __restrict__ denom,
                                                  const int* __restrict__ row_ptr,
                                                  const int* __restrict__ eids,
                                                  const int* __restrict__ src,
                                                  ushort_t* __restrict__ y, int h)
{
    const int wave = threadIdx.x >> 6, lane = threadIdx.x & 63;
    const int n = blockIdx.x * 4 + wave;
    if (n >= N_NODES) return;

    const int beg = row_ptr[n], end = row_ptr[n + 1];
    float a00 = 0.f, a01 = 0.f, a10 = 0.f, a11 = 0.f, a20 = 0.f, a21 = 0.f;

    if (beg < end) {
        const float dinv = 1.0f / denom[n * HEADS + h];
        for (int i = beg; i < end; ++i) {
            int e = eids[i];
            int s = src[e];
            float wgt = numer[(size_t)e * HEADS + h] * dinv;
            float x0 = x[(size_t)s * DIM + lane];
            float x1 = x[(size_t)s * DIM + 64 + lane];
            int r = e / NEDGE;
            if (r == 0)      { a00 = fmaf(wgt, x0, a00); a01 = fmaf(wgt, x1, a01); }
            else if (r == 1) { a10 = fmaf(wgt, x0, a10); a11 = fmaf(wgt, x1, a11); }
            else             { a20 = fmaf(wgt, x0, a20); a21 = fmaf(wgt, x1, a21); }
        }
    }
    ushort_t* yr = y + (size_t)n * (NREL * DIM);
    yr[lane]       = f2b(a00);  yr[64 + lane]  = f2b(a01);
    yr[128 + lane] = f2b(a10);  yr[192 + lane] = f2b(a11);
    yr[256 + lane] = f2b(a20);  yr[320 + lane] = f2b(a21);
}

// ---------------------------------------------------------------------------
extern "C" void kernel_launch(void* const* d_in, const int* in_sizes, int n_in,
                              void* d_out, int out_size, void* d_ws, size_t ws_size,
                              hipStream_t stream)
{
    const float* x   = (const float*)d_in[0];
    const float* WQ  = (const float*)d_in[1];
    const float* WK  = (const float*)d_in[2];
    const float* WV  = (const float*)d_in[3];
    const float* WO  = (const float*)d_in[4];
    const int*   src = (const int*)d_in[5];
    const int*   dst = (const int*)d_in[6];
    float* out = (float*)d_out;

    char* ws = (char*)d_ws;
    // union region [0, 102.4MB): q_f32 (phase 1) -> y_bf [0,38.4M) + z_bf [51.2M,102.4M) (phase 2)
    float*    q_f32 = (float*)(ws);
    ushort_t* y_bf  = (ushort_t*)(ws);
    ushort_t* z_bf  = (ushort_t*)(ws + 51200000);
    ushort_t* x_hi  = (ushort_t*)(ws + 102400000);
    ushort_t* x_lo  = (ushort_t*)(ws + 115200000);
    float*    scores= (float*)(ws + 128000000);           // later numer (in place)
    float*    denom = (float*)(ws + 130400000);
    int*      cnt     = (int*)(ws + 131200000);
    int*      row_ptr = (int*)(ws + 131400000);
    int*      cursor  = (int*)(ws + 131600016);
    int*      eids    = (int*)(ws + 131800016);
    int*      flagcnt = (int*)(ws + 132400016);
    int*      fids    = (int*)(ws + 132400032);
    ushort_t* WQt_hi = (ushort_t*)(ws + 132531104);
    ushort_t* WQt_lo = (ushort_t*)(ws + 132662176);
    ushort_t* WKt_hi = (ushort_t*)(ws + 132793248);       // [3][512][128]
    ushort_t* WKt_lo = (ushort_t*)(ws + 133186464);
    ushort_t* WOt    = (ushort_t*)(ws + 133579680);       // [128][512]
    ushort_t* WVt    = (ushort_t*)(ws + 133710752);       // [512][384]
    // total ~134.1 MB

    dim3 blk(256);

    // ---- prep ----
    cvt_x_split<<<dim3(6250), blk, 0, stream>>>(x, x_hi, x_lo);
    transpose_cvt_split<<<dim3(16, 4), blk, 0, stream>>>(WQ, WQt_hi, WQt_lo, 128, 512);
    for (int r = 0; r < NREL; ++r)
        transpose_cvt_split<<<dim3(16, 4), blk, 0, stream>>>(WK + (size_t)r * DIM * HDIM,
                                                             WKt_hi + (size_t)r * HDIM * DIM,
                                                             WKt_lo + (size_t)r * HDIM * DIM, 128, 512);
    transpose_cvt<<<dim3(4, 16), blk, 0, stream>>>(WO, WOt, 512, 128);
    transpose_cvt<<<dim3(16, 12), blk, 0, stream>>>(WV, WVt, 384, 512);

    hipMemsetAsync(cnt,     0, (size_t)N_NODES * sizeof(int), stream);
    hipMemsetAsync(denom,   0, (size_t)N_NODES * HEADS * sizeof(float), stream);
    hipMemsetAsync(flagcnt, 0, 16, stream);

    // ---- CSR by dst ----
    csr_count<<<dim3((NETOT + 255) / 256), blk, 0, stream>>>(dst, cnt);
    csr_scan<<<dim3(1), dim3(1024), 0, stream>>>(cnt, row_ptr, cursor);
    csr_fill<<<dim3((NETOT + 255) / 256), blk, 0, stream>>>(dst, cursor, eids);

    const int MB = (N_NODES + 127) / 128;   // 391

    // ---- q = x @ WQ, near-f32 via 3-term split ----
    gemm_split<<<dim3(MB, 4), blk, 0, stream>>>(x_hi, x_lo, WQt_hi, WQt_lo, q_f32, N_NODES);

    // ---- fused scores per relation (split K on the fly, dot with q) ----
    for (int r = 0; r < NREL; ++r)
        scores_fused<<<dim3(MB), blk, 0, stream>>>(x_hi, x_lo,
                                                   WKt_hi + (size_t)r * HDIM * DIM,
                                                   WKt_lo + (size_t)r * HDIM * DIM,
                                                   q_f32, src + r * NEDGE, dst + r * NEDGE,
                                                   scores + (size_t)r * NEDGE * HEADS, r,
                                                   flagcnt, fids);

    // ---- exact f32 repair of near-zero scores ----
    repair_kernel<<<dim3(FLAG_CAP / 4), blk, 0, stream>>>(x, WQ, WK, src, dst,
                                                          flagcnt, fids, scores);

    // ---- numer (in place) + denom ----
    numer_denom<<<dim3((NETOT * HEADS + 255) / 256), blk, 0, stream>>>(scores, dst, denom);

    // ---- per head: aggregation then dense GEMM into z ----
    for (int h = 0; h < HEADS; ++h) {
        agg_kernel<<<dim3((N_NODES + 3) / 4), blk, 0, stream>>>(
            x, scores, denom, row_ptr, eids, src, y_bf, h);
        gemm_mfma<1><<<dim3(MB, 1), blk, 0, stream>>>(y_bf, WVt + (size_t)h * 128 * 384,
                                                      z_bf + h * 128, N_NODES, NREL * DIM, HDIM);
    }

    // ---- out = z @ WO (f32) ----
    gemm_mfma<0><<<dim3(MB, 1), blk, 0, stream>>>(z_bf, WOt, out, N_NODES, HDIM, DIM);
}

// Round 6
// 596.829 us; speedup vs baseline: 4.4515x; 1.4017x over previous
//
#include <hip/hip_runtime.h>
#include <stdint.h>

// Problem constants (RelationalAttentionLayer)
#define N_NODES 50000
#define DIM     128
#define HEADS   4
#define HDIM    512      // HEADS * DIM
#define NREL    3
#define NEDGE   50000    // edges per relation
#define NETOT   150000   // total edges
#define FLAG_CAP 32768
#define NSCAN_BLK 196    // ceil(50000/256)

constexpr float EPS_F  = 1e-10f;
constexpr float SCALE  = 0.044194173824159216f;  // 1/sqrt(512)
constexpr float TAU    = 0.005f;                 // exact-repair band

typedef unsigned short ushort_t;
typedef __attribute__((ext_vector_type(8))) short  short8;
typedef __attribute__((ext_vector_type(4))) unsigned short ushort4v;
typedef __attribute__((ext_vector_type(4))) float  f32x4;

__device__ __forceinline__ float b2f(ushort_t u) {
    unsigned int v = ((unsigned int)u) << 16;
    float f; __builtin_memcpy(&f, &v, 4); return f;
}
__device__ __forceinline__ ushort_t f2b(float f) {
    unsigned int v; __builtin_memcpy(&v, &f, 4);
    unsigned int r = v + 0x7FFFu + ((v >> 16) & 1u);   // RNE
    return (ushort_t)(r >> 16);
}

#define LDSTRIDE 40   // ushort stride per 32-elem k-row (80B; 16B slots; 2-way alias free)

// ---------------------------------------------------------------------------
// bf16 MFMA GEMM: C[M,N] = A[M,K] @ Bt[N][K]^T. 128x128 tile, BK=32, 4 waves.
// ---------------------------------------------------------------------------
template <int OUTMODE>   // 0 = f32 store, 1 = bf16 store
__global__ __launch_bounds__(256) void gemm_mfma(const ushort_t* __restrict__ A,
                                                 const ushort_t* __restrict__ Bt,
                                                 void* __restrict__ Cv,
                                                 int M, int K, int ldc)
{
    __shared__ ushort_t As[128 * LDSTRIDE];
    __shared__ ushort_t Bs[128 * LDSTRIDE];

    const int tid = threadIdx.x;
    const int w = tid >> 6, l = tid & 63;
    const int bm = blockIdx.x, bn = blockIdx.y;
    const int wr = w >> 1, wc = w & 1;

    int s_ro[2]; size_t s_ao[2], s_bo[2];
#pragma unroll
    for (int i = 0; i < 2; ++i) {
        int c = tid + 256 * i;
        int row = c >> 2, slot = c & 3;
        s_ro[i] = row * LDSTRIDE + slot * 8;
        int grow = bm * 128 + row; if (grow >= M) grow = M - 1;
        s_ao[i] = (size_t)grow * K + slot * 8;
        s_bo[i] = (size_t)(bn * 128 + row) * K + slot * 8;
    }

    int a_off[4], b_off[4];
#pragma unroll
    for (int mi = 0; mi < 4; ++mi)
        a_off[mi] = (wr * 64 + mi * 16 + (l & 15)) * LDSTRIDE + (l >> 4) * 8;
#pragma unroll
    for (int ni = 0; ni < 4; ++ni)
        b_off[ni] = (wc * 64 + ni * 16 + (l & 15)) * LDSTRIDE + (l >> 4) * 8;

    f32x4 acc[4][4] = {};

    for (int kk = 0; kk < K; kk += 32) {
        __syncthreads();
#pragma unroll
        for (int i = 0; i < 2; ++i) {
            *(short8*)&As[s_ro[i]] = *(const short8*)(A  + s_ao[i] + kk);
            *(short8*)&Bs[s_ro[i]] = *(const short8*)(Bt + s_bo[i] + kk);
        }
        __syncthreads();

        short8 af[4], bfr[4];
#pragma unroll
        for (int mi = 0; mi < 4; ++mi) af[mi]  = *(const short8*)&As[a_off[mi]];
#pragma unroll
        for (int ni = 0; ni < 4; ++ni) bfr[ni] = *(const short8*)&Bs[b_off[ni]];

#pragma unroll
        for (int mi = 0; mi < 4; ++mi)
#pragma unroll
            for (int ni = 0; ni < 4; ++ni)
                acc[mi][ni] = __builtin_amdgcn_mfma_f32_16x16x32_bf16(af[mi], bfr[ni], acc[mi][ni], 0, 0, 0);
    }

#pragma unroll
    for (int mi = 0; mi < 4; ++mi)
#pragma unroll
        for (int j = 0; j < 4; ++j) {
            int row = bm * 128 + wr * 64 + mi * 16 + (l >> 4) * 4 + j;
            if (row < M) {
#pragma unroll
                for (int ni = 0; ni < 4; ++ni) {
                    int col = bn * 128 + wc * 64 + ni * 16 + (l & 15);
                    if (OUTMODE == 1)
                        ((ushort_t*)Cv)[(size_t)row * ldc + col] = f2b(acc[mi][ni][j]);
                    else
                        ((float*)Cv)[(size_t)row * ldc + col] = acc[mi][ni][j];
                }
            }
        }
}

// ---------------------------------------------------------------------------
// Split-bf16 dense GEMM (3-term, near-f32): C = (Ah+Al)[M,128] @ (Bh+Bl)t[512][128]
// f32 out, ldc=512. Used for q = x @ WQ.
// ---------------------------------------------------------------------------
__global__ __launch_bounds__(256) void gemm_split(const ushort_t* __restrict__ Ahg,
                                                  const ushort_t* __restrict__ Alg,
                                                  const ushort_t* __restrict__ Bhg,
                                                  const ushort_t* __restrict__ Blg,
                                                  float* __restrict__ C, int M)
{
    __shared__ ushort_t Ah[128 * LDSTRIDE], Al[128 * LDSTRIDE];
    __shared__ ushort_t Bh[128 * LDSTRIDE], Bl[128 * LDSTRIDE];

    const int tid = threadIdx.x;
    const int w = tid >> 6, l = tid & 63;
    const int bm = blockIdx.x, bn = blockIdx.y;
    const int wr = w >> 1, wc = w & 1;

    int s_ro[2]; size_t s_ao[2], s_bo[2];
#pragma unroll
    for (int i = 0; i < 2; ++i) {
        int c = tid + 256 * i;
        int row = c >> 2, slot = c & 3;
        s_ro[i] = row * LDSTRIDE + slot * 8;
        int grow = bm * 128 + row; if (grow >= M) grow = M - 1;
        s_ao[i] = (size_t)grow * 128 + slot * 8;
        s_bo[i] = (size_t)(bn * 128 + row) * 128 + slot * 8;
    }

    int a_off[4], b_off[4];
#pragma unroll
    for (int mi = 0; mi < 4; ++mi)
        a_off[mi] = (wr * 64 + mi * 16 + (l & 15)) * LDSTRIDE + (l >> 4) * 8;
#pragma unroll
    for (int ni = 0; ni < 4; ++ni)
        b_off[ni] = (wc * 64 + ni * 16 + (l & 15)) * LDSTRIDE + (l >> 4) * 8;

    f32x4 acc[4][4] = {};

    for (int kk = 0; kk < 128; kk += 32) {
        __syncthreads();
#pragma unroll
        for (int i = 0; i < 2; ++i) {
            *(short8*)&Ah[s_ro[i]] = *(const short8*)(Ahg + s_ao[i] + kk);
            *(short8*)&Al[s_ro[i]] = *(const short8*)(Alg + s_ao[i] + kk);
            *(short8*)&Bh[s_ro[i]] = *(const short8*)(Bhg + s_bo[i] + kk);
            *(short8*)&Bl[s_ro[i]] = *(const short8*)(Blg + s_bo[i] + kk);
        }
        __syncthreads();

        short8 ah[4], al[4], bh[4], bl[4];
#pragma unroll
        for (int mi = 0; mi < 4; ++mi) { ah[mi] = *(const short8*)&Ah[a_off[mi]];
                                         al[mi] = *(const short8*)&Al[a_off[mi]]; }
#pragma unroll
        for (int ni = 0; ni < 4; ++ni) { bh[ni] = *(const short8*)&Bh[b_off[ni]];
                                         bl[ni] = *(const short8*)&Bl[b_off[ni]]; }

#pragma unroll
        for (int mi = 0; mi < 4; ++mi)
#pragma unroll
            for (int ni = 0; ni < 4; ++ni) {
                acc[mi][ni] = __builtin_amdgcn_mfma_f32_16x16x32_bf16(ah[mi], bh[ni], acc[mi][ni], 0, 0, 0);
                acc[mi][ni] = __builtin_amdgcn_mfma_f32_16x16x32_bf16(ah[mi], bl[ni], acc[mi][ni], 0, 0, 0);
                acc[mi][ni] = __builtin_amdgcn_mfma_f32_16x16x32_bf16(al[mi], bh[ni], acc[mi][ni], 0, 0, 0);
            }
    }

#pragma unroll
    for (int mi = 0; mi < 4; ++mi)
#pragma unroll
        for (int j = 0; j < 4; ++j) {
            int row = bm * 128 + wr * 64 + mi * 16 + (l >> 4) * 4 + j;
            if (row < M) {
#pragma unroll
                for (int ni = 0; ni < 4; ++ni) {
                    int col = bn * 128 + wc * 64 + ni * 16 + (l & 15);
                    C[(size_t)row * 512 + col] = acc[mi][ni][j];
                }
            }
        }
}

// ---------------------------------------------------------------------------
// Fused scores (unchanged from round 5): split-MFMA gathered K, dot with q.
// ---------------------------------------------------------------------------
__global__ __launch_bounds__(256) void scores_fused(const ushort_t* __restrict__ xh,
                                                    const ushort_t* __restrict__ xl,
                                                    const ushort_t* __restrict__ Wh,
                                                    const ushort_t* __restrict__ Wl,
                                                    const float* __restrict__ q,
                                                    const int* __restrict__ srcr,
                                                    const int* __restrict__ dstr,
                                                    float* __restrict__ sc_out,
                                                    int rel,
                                                    int* __restrict__ flagcnt,
                                                    int* __restrict__ fids)
{
    __shared__ ushort_t Ah[128 * LDSTRIDE], Al[128 * LDSTRIDE];
    __shared__ ushort_t Bh[128 * LDSTRIDE], Bl[128 * LDSTRIDE];
    __shared__ float sc_red[128][2];

    const int tid = threadIdx.x;
    const int w = tid >> 6, l = tid & 63;
    const int bm = blockIdx.x;
    const int wr = w >> 1, wc = w & 1;

    int s_ro[2], s_row[2], s_slot[2], s_arow[2];
#pragma unroll
    for (int i = 0; i < 2; ++i) {
        int c = tid + 256 * i;
        s_row[i] = c >> 2; s_slot[i] = c & 3;
        s_ro[i] = s_row[i] * LDSTRIDE + s_slot[i] * 8;
        int e = bm * 128 + s_row[i]; if (e >= NEDGE) e = NEDGE - 1;
        s_arow[i] = srcr[e];
    }

    int a_off[4], b_off[4];
#pragma unroll
    for (int mi = 0; mi < 4; ++mi)
        a_off[mi] = (wr * 64 + mi * 16 + (l & 15)) * LDSTRIDE + (l >> 4) * 8;
#pragma unroll
    for (int ni = 0; ni < 4; ++ni)
        b_off[ni] = (wc * 64 + ni * 16 + (l & 15)) * LDSTRIDE + (l >> 4) * 8;

    for (int nc = 0; nc < 4; ++nc) {        // n-chunk == head
        f32x4 acc[4][4] = {};
        for (int kk = 0; kk < 128; kk += 32) {
            __syncthreads();
#pragma unroll
            for (int i = 0; i < 2; ++i) {
                size_t ao = (size_t)s_arow[i] * 128 + kk + s_slot[i] * 8;
                *(short8*)&Ah[s_ro[i]] = *(const short8*)(xh + ao);
                *(short8*)&Al[s_ro[i]] = *(const short8*)(xl + ao);
                size_t bo = (size_t)(nc * 128 + s_row[i]) * 128 + kk + s_slot[i] * 8;
                *(short8*)&Bh[s_ro[i]] = *(const short8*)(Wh + bo);
                *(short8*)&Bl[s_ro[i]] = *(const short8*)(Wl + bo);
            }
            __syncthreads();

            short8 ah[4], al[4], bh[4], bl[4];
#pragma unroll
            for (int mi = 0; mi < 4; ++mi) { ah[mi] = *(const short8*)&Ah[a_off[mi]];
                                             al[mi] = *(const short8*)&Al[a_off[mi]]; }
#pragma unroll
            for (int ni = 0; ni < 4; ++ni) { bh[ni] = *(const short8*)&Bh[b_off[ni]];
                                             bl[ni] = *(const short8*)&Bl[b_off[ni]]; }
#pragma unroll
            for (int mi = 0; mi < 4; ++mi)
#pragma unroll
                for (int ni = 0; ni < 4; ++ni) {
                    acc[mi][ni] = __builtin_amdgcn_mfma_f32_16x16x32_bf16(ah[mi], bh[ni], acc[mi][ni], 0, 0, 0);
                    acc[mi][ni] = __builtin_amdgcn_mfma_f32_16x16x32_bf16(ah[mi], bl[ni], acc[mi][ni], 0, 0, 0);
                    acc[mi][ni] = __builtin_amdgcn_mfma_f32_16x16x32_bf16(al[mi], bh[ni], acc[mi][ni], 0, 0, 0);
                }
        }

#pragma unroll
        for (int mi = 0; mi < 4; ++mi)
#pragma unroll
            for (int j = 0; j < 4; ++j) {
                int e_loc = wr * 64 + mi * 16 + (l >> 4) * 4 + j;
                int e = bm * 128 + e_loc; int ec = (e < NEDGE) ? e : NEDGE - 1;
                int d = dstr[ec];
                const float* qr = q + (size_t)d * HDIM + nc * 128 + wc * 64 + (l & 15);
                float p = acc[mi][0][j] * qr[0]  + acc[mi][1][j] * qr[16]
                        + acc[mi][2][j] * qr[32] + acc[mi][3][j] * qr[48];
                p += __shfl_xor(p, 1); p += __shfl_xor(p, 2);
                p += __shfl_xor(p, 4); p += __shfl_xor(p, 8);
                if ((l & 15) == 0) sc_red[e_loc][wc] = p;
            }
        __syncthreads();

        if (tid < 128) {
            int e = bm * 128 + tid;
            if (e < NEDGE) {
                float s = (sc_red[tid][0] + sc_red[tid][1]) * SCALE;
                sc_out[(size_t)e * HEADS + nc] = s;
                if (fabsf(s) < TAU) {
                    int pos = atomicAdd(flagcnt, 1);
                    if (pos < FLAG_CAP) fids[pos] = (rel * NEDGE + e) * HEADS + nc;
                }
            }
        }
        __syncthreads();
    }
}

// ---------------------------------------------------------------------------
// Exact f32 repair of near-zero scores.
// ---------------------------------------------------------------------------
__global__ __launch_bounds__(256) void repair_kernel(const float* __restrict__ x,
                                                     const float* __restrict__ WQ,
                                                     const float* __restrict__ WK,
                                                     const int* __restrict__ src,
                                                     const int* __restrict__ dst,
                                                     const int* __restrict__ flagcnt,
                                                     const int* __restrict__ fids,
                                                     float* __restrict__ scores)
{
    int wid = blockIdx.x * 4 + (threadIdx.x >> 6);
    int l = threadIdx.x & 63;
    int nf = *flagcnt; if (nf > FLAG_CAP) nf = FLAG_CAP;
    if (wid >= nf) return;
    int p = fids[wid];
    int h = p & 3; int eg = p >> 2; int r = eg / NEDGE;
    int s = src[eg], d = dst[eg];
    const float* xs = x + (size_t)s * DIM;
    const float* xd = x + (size_t)d * DIM;
    const float* wq = WQ + h * DIM;
    const float* wk = WK + (size_t)r * DIM * HDIM + h * DIM;

    float tot = 0.f;
#pragma unroll 1
    for (int j = 0; j < 2; ++j) {
        int c = j * 64 + l;
        float qc = 0.f, kc = 0.f;
        for (int dd = 0; dd < DIM; ++dd) {
            qc = fmaf(xd[dd], wq[(size_t)dd * HDIM + c], qc);
            kc = fmaf(xs[dd], wk[(size_t)dd * HDIM + c], kc);
        }
        tot = fmaf(qc, kc, tot);
    }
    tot += __shfl_xor(tot, 1);  tot += __shfl_xor(tot, 2);
    tot += __shfl_xor(tot, 4);  tot += __shfl_xor(tot, 8);
    tot += __shfl_xor(tot, 16); tot += __shfl_xor(tot, 32);
    if (l == 0) scores[p] = tot * SCALE;
}

// ---------------------------------------------------------------------------
// numer = relu(s)^2 + eps (in place) ; atomic denom
// ---------------------------------------------------------------------------
__global__ __launch_bounds__(256) void numer_denom(float* __restrict__ scores,
                                                   const int* __restrict__ dst,
                                                   float* __restrict__ denom)
{
    int p = blockIdx.x * 256 + threadIdx.x;
    if (p < NETOT * HEADS) {
        float s = scores[p];
        float m = fmaxf(s, 0.f);
        float nu = m * m + EPS_F;
        scores[p] = nu;
        atomicAdd(&denom[dst[p >> 2] * HEADS + (p & 3)], nu);
    }
}

// ---------------------------------------------------------------------------
// prep kernels
// ---------------------------------------------------------------------------
__global__ __launch_bounds__(256) void cvt_x_split(const float* __restrict__ x,
                                                   ushort_t* __restrict__ xh,
                                                   ushort_t* __restrict__ xl)
{
    int i = (blockIdx.x * 256 + threadIdx.x) * 4;
    float4 v = *reinterpret_cast<const float4*>(x + i);
    ushort_t h0 = f2b(v.x), h1 = f2b(v.y), h2 = f2b(v.z), h3 = f2b(v.w);
    ushort4v oh = {h0, h1, h2, h3};
    ushort4v ol = {f2b(v.x - b2f(h0)), f2b(v.y - b2f(h1)),
                   f2b(v.z - b2f(h2)), f2b(v.w - b2f(h3))};
    *reinterpret_cast<ushort4v*>(xh + i) = oh;
    *reinterpret_cast<ushort4v*>(xl + i) = ol;
}

// split transpose: hi/lo pair. out[C][R] = transpose(in[R][C] f32)
__global__ __launch_bounds__(256) void transpose_cvt_split(const float* __restrict__ in,
                                                           ushort_t* __restrict__ oh,
                                                           ushort_t* __restrict__ ol,
                                                           int R, int C)
{
    __shared__ float t[32][33];
    int x = threadIdx.x & 31, y0 = threadIdx.x >> 5;
    int br = blockIdx.y, bc = blockIdx.x;
#pragma unroll
    for (int k = 0; k < 4; ++k)
        t[y0 + k * 8][x] = in[(size_t)(br * 32 + y0 + k * 8) * C + bc * 32 + x];
    __syncthreads();
#pragma unroll
    for (int k = 0; k < 4; ++k) {
        int c = bc * 32 + y0 + k * 8;
        float v = t[x][y0 + k * 8];
        ushort_t hv = f2b(v);
        oh[(size_t)c * R + br * 32 + x] = hv;
        ol[(size_t)c * R + br * 32 + x] = f2b(v - b2f(hv));
    }
}

// ---------------------------------------------------------------------------
// W2 composite: W2t[j][h*384 + r*128 + d] = sum_c WV[r][d][h*128+c] * WO[h*128+c][j]
// f32 accumulate from f32 inputs, bf16 store. Block: 256 = 2 hk x 128 j.
// ---------------------------------------------------------------------------
__global__ __launch_bounds__(256) void w2_kernel(const float* __restrict__ WV,
                                                 const float* __restrict__ WO,
                                                 ushort_t* __restrict__ W2t)
{
    int j = threadIdx.x & 127;
    int hk = blockIdx.x * 2 + (threadIdx.x >> 7);   // 0..1535
    int h = hk / 384, kk = hk % 384;
    int r = kk >> 7, d = kk & 127;
    const float* wv = WV + (size_t)r * DIM * HDIM + (size_t)d * HDIM + h * DIM;
    const float* wo = WO + (size_t)(h * DIM) * DIM + j;
    float acc = 0.f;
#pragma unroll 4
    for (int c = 0; c < DIM; ++c)
        acc = fmaf(wv[c], wo[(size_t)c * DIM], acc);
    W2t[(size_t)j * 1536 + hk] = f2b(acc);
}

// ---------------------------------------------------------------------------
// CSR build: count, then 3-kernel hierarchical exclusive scan, then fill.
// ---------------------------------------------------------------------------
__global__ __launch_bounds__(256) void csr_count(const int* __restrict__ dst, int* __restrict__ cnt)
{
    int e = blockIdx.x * 256 + threadIdx.x;
    if (e < NETOT) atomicAdd(&cnt[dst[e]], 1);
}

__global__ __launch_bounds__(256) void scan_blksum(const int* __restrict__ cnt,
                                                   int* __restrict__ blksum)
{
    __shared__ int red[4];
    int tid = threadIdx.x, lane = tid & 63, wave = tid >> 6;
    int i = blockIdx.x * 256 + tid;
    int v = (i < N_NODES) ? cnt[i] : 0;
#pragma unroll
    for (int off = 32; off > 0; off >>= 1) v += __shfl_down(v, off);
    if (lane == 0) red[wave] = v;
    __syncthreads();
    if (tid == 0) blksum[blockIdx.x] = red[0] + red[1] + red[2] + red[3];
}

__global__ __launch_bounds__(256) void scan_top(const int* __restrict__ blksum,
                                                int* __restrict__ blkoff,
                                                int* __restrict__ row_ptr)
{
    __shared__ int s[256];
    int t = threadIdx.x;
    int v = (t < NSCAN_BLK) ? blksum[t] : 0;
    s[t] = v;
    __syncthreads();
    for (int off = 1; off < 256; off <<= 1) {
        int u = (t >= off) ? s[t - off] : 0;
        __syncthreads();
        s[t] += u;
        __syncthreads();
    }
    if (t < NSCAN_BLK) blkoff[t] = s[t] - v;   // exclusive
    if (t == NSCAN_BLK - 1) row_ptr[N_NODES] = s[t];
}

__global__ __launch_bounds__(256) void scan_fin(const int* __restrict__ cnt,
                                                const int* __restrict__ blkoff,
                                                int* __restrict__ row_ptr,
                                                int* __restrict__ cursor)
{
    __shared__ int s[256];
    int t = threadIdx.x, i = blockIdx.x * 256 + t;
    int v = (i < N_NODES) ? cnt[i] : 0;
    s[t] = v;
    __syncthreads();
    for (int off = 1; off < 256; off <<= 1) {
        int u = (t >= off) ? s[t - off] : 0;
        __syncthreads();
        s[t] += u;
        __syncthreads();
    }
    if (i < N_NODES) {
        int val = blkoff[blockIdx.x] + s[t] - v;
        row_ptr[i] = val;
        cursor[i]  = val;
    }
}

__global__ __launch_bounds__(256) void csr_fill(const int* __restrict__ dst,
                                                int* __restrict__ cursor,
                                                int* __restrict__ eids)
{
    int e = blockIdx.x * 256 + threadIdx.x;
    if (e < NETOT) {
        int pos = atomicAdd(&cursor[dst[e]], 1);
        eids[pos] = e;
    }
}

// ---------------------------------------------------------------------------
// agg_all: one wave per node, ALL 4 heads in one pass (x gathered once).
//   y_cat[n][h*384 + r*128 + d] = sum_{e->n, rel r} (numer[e,h]/denom[n,h]) * x[src_e, d]
// ---------------------------------------------------------------------------
__global__ __launch_bounds__(256) void agg_all(const float* __restrict__ x,
                                               const float* __restrict__ numer,
                                               const float* __restrict__ denom,
                                               const int* __restrict__ row_ptr,
                                               const int* __restrict__ eids,
                                               const int* __restrict__ src,
                                               ushort_t* __restrict__ y)
{
    const int wave = threadIdx.x >> 6, lane = threadIdx.x & 63;
    const int n = blockIdx.x * 4 + wave;
    if (n >= N_NODES) return;

    const int beg = row_ptr[n], end = row_ptr[n + 1];
    float acc[NREL][HEADS][2] = {};

    if (beg < end) {
        float4 dn = *reinterpret_cast<const float4*>(&denom[n * HEADS]);
        float di[HEADS] = {1.f / dn.x, 1.f / dn.y, 1.f / dn.z, 1.f / dn.w};
        for (int i = beg; i < end; ++i) {
            int e = eids[i];
            int s = src[e];
            float4 nu = *reinterpret_cast<const float4*>(&numer[(size_t)e * HEADS]);
            float wv[HEADS] = {nu.x * di[0], nu.y * di[1], nu.z * di[2], nu.w * di[3]};
            float x0 = x[(size_t)s * DIM + lane];
            float x1 = x[(size_t)s * DIM + 64 + lane];
            int r = e / NEDGE;   // wave-uniform per iteration
            if (r == 0) {
#pragma unroll
                for (int h = 0; h < HEADS; ++h) {
                    acc[0][h][0] = fmaf(wv[h], x0, acc[0][h][0]);
                    acc[0][h][1] = fmaf(wv[h], x1, acc[0][h][1]);
                }
            } else if (r == 1) {
#pragma unroll
                for (int h = 0; h < HEADS; ++h) {
                    acc[1][h][0] = fmaf(wv[h], x0, acc[1][h][0]);
                    acc[1][h][1] = fmaf(wv[h], x1, acc[1][h][1]);
                }
            } else {
#pragma unroll
                for (int h = 0; h < HEADS; ++h) {
                    acc[2][h][0] = fmaf(wv[h], x0, acc[2][h][0]);
                    acc[2][h][1] = fmaf(wv[h], x1, acc[2][h][1]);
                }
            }
        }
    }

    ushort_t* yr = y + (size_t)n * 1536;
#pragma unroll
    for (int h = 0; h < HEADS; ++h)
#pragma unroll
        for (int r = 0; r < NREL; ++r) {
            yr[h * 384 + r * 128 + lane]      = f2b(acc[r][h][0]);
            yr[h * 384 + r * 128 + 64 + lane] = f2b(acc[r][h][1]);
        }
}

// ---------------------------------------------------------------------------
extern "C" void kernel_launch(void* const* d_in, const int* in_sizes, int n_in,
                              void* d_out, int out_size, void* d_ws, size_t ws_size,
                              hipStream_t stream)
{
    const float* x   = (const float*)d_in[0];
    const float* WQ  = (const float*)d_in[1];
    const float* WK  = (const float*)d_in[2];
    const float* WV  = (const float*)d_in[3];
    const float* WO  = (const float*)d_in[4];
    const int*   src = (const int*)d_in[5];
    const int*   dst = (const int*)d_in[6];
    float* out = (float*)d_out;

    char* ws = (char*)d_ws;
    // small, persistent region first
    float*    scores  = (float*)(ws);                    // 2,400,000 (later numer in place)
    float*    denom   = (float*)(ws + 2400000);          //   800,000
    int*      cnt     = (int*)(ws + 3200000);            //   200,000
    int*      row_ptr = (int*)(ws + 3400000);            //   200,004 (pad to 3,600,016)
    int*      cursor  = (int*)(ws + 3600016);            //   200,000
    int*      eids    = (int*)(ws + 3800016);            //   600,000
    int*      flagcnt = (int*)(ws + 4400016);            //        16
    int*      fids    = (int*)(ws + 4400032);            //   131,072
    int*      blksum  = (int*)(ws + 4531104);            //       784 -> pad
    int*      blkoff  = (int*)(ws + 4532144);            //       784 -> pad
    ushort_t* WQt_hi  = (ushort_t*)(ws + 4533184);       //   131,072
    ushort_t* WQt_lo  = (ushort_t*)(ws + 4664256);       //   131,072
    ushort_t* WKt_hi  = (ushort_t*)(ws + 4795328);       //   393,216 [3][512][128]
    ushort_t* WKt_lo  = (ushort_t*)(ws + 5188544);       //   393,216
    ushort_t* W2t     = (ushort_t*)(ws + 5581760);       //   393,216 [128][1536]
    // big overlaid region, base 6,000,000:
    //   phase A: x_hi [6.0M,18.8M) x_lo [18.8M,31.6M) q_f32 [31.6M,134.0M)
    //   phase B: y_cat [6.0M,159.6M) bf16 [N][1536]   (x_hi/x_lo/q all dead)
    ushort_t* x_hi  = (ushort_t*)(ws + 6000000);
    ushort_t* x_lo  = (ushort_t*)(ws + 18800000);
    float*    q_f32 = (float*)(ws + 31600000);
    ushort_t* y_cat = (ushort_t*)(ws + 6000000);
    // peak usage ~159.6 MB (ws >= 208 MB proven in round 1)

    dim3 blk(256);

    // ---- prep ----
    cvt_x_split<<<dim3(6250), blk, 0, stream>>>(x, x_hi, x_lo);
    transpose_cvt_split<<<dim3(16, 4), blk, 0, stream>>>(WQ, WQt_hi, WQt_lo, 128, 512);
    for (int r = 0; r < NREL; ++r)
        transpose_cvt_split<<<dim3(16, 4), blk, 0, stream>>>(WK + (size_t)r * DIM * HDIM,
                                                             WKt_hi + (size_t)r * HDIM * DIM,
                                                             WKt_lo + (size_t)r * HDIM * DIM, 128, 512);
    w2_kernel<<<dim3(768), blk, 0, stream>>>(WV, WO, W2t);

    hipMemsetAsync(cnt,     0, (size_t)N_NODES * sizeof(int), stream);
    hipMemsetAsync(denom,   0, (size_t)N_NODES * HEADS * sizeof(float), stream);
    hipMemsetAsync(flagcnt, 0, 16, stream);

    // ---- CSR by dst (parallel scan) ----
    csr_count<<<dim3((NETOT + 255) / 256), blk, 0, stream>>>(dst, cnt);
    scan_blksum<<<dim3(NSCAN_BLK), blk, 0, stream>>>(cnt, blksum);
    scan_top<<<dim3(1), blk, 0, stream>>>(blksum, blkoff, row_ptr);
    scan_fin<<<dim3(NSCAN_BLK), blk, 0, stream>>>(cnt, blkoff, row_ptr, cursor);
    csr_fill<<<dim3((NETOT + 255) / 256), blk, 0, stream>>>(dst, cursor, eids);

    const int MB = (N_NODES + 127) / 128;   // 391

    // ---- q = x @ WQ, near-f32 via 3-term split ----
    gemm_split<<<dim3(MB, 4), blk, 0, stream>>>(x_hi, x_lo, WQt_hi, WQt_lo, q_f32, N_NODES);

    // ---- fused scores per relation ----
    for (int r = 0; r < NREL; ++r)
        scores_fused<<<dim3(MB), blk, 0, stream>>>(x_hi, x_lo,
                                                   WKt_hi + (size_t)r * HDIM * DIM,
                                                   WKt_lo + (size_t)r * HDIM * DIM,
                                                   q_f32, src + r * NEDGE, dst + r * NEDGE,
                                                   scores + (size_t)r * NEDGE * HEADS, r,
                                                   flagcnt, fids);

    // ---- exact f32 repair of near-zero scores ----
    repair_kernel<<<dim3(FLAG_CAP / 4), blk, 0, stream>>>(x, WQ, WK, src, dst,
                                                          flagcnt, fids, scores);

    // ---- numer (in place) + denom ----
    numer_denom<<<dim3((NETOT * HEADS + 255) / 256), blk, 0, stream>>>(scores, dst, denom);

    // ---- aggregation: all 4 heads in one pass -> y_cat [N][1536] ----
    agg_all<<<dim3((N_NODES + 3) / 4), blk, 0, stream>>>(
        x, scores, denom, row_ptr, eids, src, y_cat);

    // ---- out = y_cat @ W2 (one MFMA GEMM, f32 out) ----
    gemm_mfma<0><<<dim3(MB, 1), blk, 0, stream>>>(y_cat, W2t, out, N_NODES, 1536, DIM);
}

// Round 7
// 447.496 us; speedup vs baseline: 5.9370x; 1.3337x over previous
//
#include <hip/hip_runtime.h>
#include <stdint.h>

// Problem constants (RelationalAttentionLayer)
#define N_NODES 50000
#define DIM     128
#define HEADS   4
#define HDIM    512      // HEADS * DIM
#define NREL    3
#define NEDGE   50000    // edges per relation
#define NETOT   150000   // total edges
#define FLAG_CAP 32768
#define NSCAN_BLK 196    // ceil(50000/256)

constexpr float EPS_F  = 1e-10f;
constexpr float SCALE  = 0.044194173824159216f;  // 1/sqrt(512)
constexpr float TAU    = 0.005f;                 // exact-repair band

typedef unsigned short ushort_t;
typedef __attribute__((ext_vector_type(8))) short  short8;
typedef __attribute__((ext_vector_type(4))) unsigned short ushort4v;
typedef __attribute__((ext_vector_type(4))) float  f32x4;

__device__ __forceinline__ float b2f(ushort_t u) {
    unsigned int v = ((unsigned int)u) << 16;
    float f; __builtin_memcpy(&f, &v, 4); return f;
}
__device__ __forceinline__ ushort_t f2b(float f) {
    unsigned int v; __builtin_memcpy(&v, &f, 4);
    unsigned int r = v + 0x7FFFu + ((v >> 16) & 1u);   // RNE
    return (ushort_t)(r >> 16);
}

#define LDSTRIDE 40   // ushort stride per 32-elem k-row (80B; 16B slots; 2-way alias free)

// ---------------------------------------------------------------------------
// bf16 MFMA GEMM: C[M,N] = A[M,K] @ Bt[N][K]^T. BM x 128 tile, BK=32, 4 waves.
// BM in {64,128}. Register-prefetch of next k-slice.
// ---------------------------------------------------------------------------
template <int OUTMODE, int BM>   // OUTMODE: 0 = f32 store, 1 = bf16 store
__global__ __launch_bounds__(256) void gemm_mfma(const ushort_t* __restrict__ A,
                                                 const ushort_t* __restrict__ Bt,
                                                 void* __restrict__ Cv,
                                                 int M, int K, int ldc)
{
    constexpr int MFR = BM / 32;        // M-frags per wave (128->4, 64->2)
    constexpr int ACH = BM * 4 / 256;   // A chunks per thread (128->2, 64->1)

    __shared__ ushort_t As[BM * LDSTRIDE];
    __shared__ ushort_t Bs[128 * LDSTRIDE];

    const int tid = threadIdx.x;
    const int w = tid >> 6, l = tid & 63;
    const int bm = blockIdx.x, bn = blockIdx.y;
    const int wr = w >> 1, wc = w & 1;

    int sa_ro[ACH]; size_t sa_o[ACH];
#pragma unroll
    for (int i = 0; i < ACH; ++i) {
        int c = tid + 256 * i;
        int row = c >> 2, slot = c & 3;
        sa_ro[i] = row * LDSTRIDE + slot * 8;
        int grow = bm * BM + row; if (grow >= M) grow = M - 1;
        sa_o[i] = (size_t)grow * K + slot * 8;
    }
    int sb_ro[2]; size_t sb_o[2];
#pragma unroll
    for (int i = 0; i < 2; ++i) {
        int c = tid + 256 * i;
        int row = c >> 2, slot = c & 3;
        sb_ro[i] = row * LDSTRIDE + slot * 8;
        sb_o[i] = (size_t)(bn * 128 + row) * K + slot * 8;
    }

    int a_off[MFR], b_off[4];
#pragma unroll
    for (int mi = 0; mi < MFR; ++mi)
        a_off[mi] = (wr * (BM / 2) + mi * 16 + (l & 15)) * LDSTRIDE + (l >> 4) * 8;
#pragma unroll
    for (int ni = 0; ni < 4; ++ni)
        b_off[ni] = (wc * 64 + ni * 16 + (l & 15)) * LDSTRIDE + (l >> 4) * 8;

    f32x4 acc[MFR][4] = {};

    short8 av[ACH], bv[2];
#pragma unroll
    for (int i = 0; i < ACH; ++i) av[i] = *(const short8*)(A + sa_o[i]);
#pragma unroll
    for (int i = 0; i < 2; ++i)   bv[i] = *(const short8*)(Bt + sb_o[i]);

    for (int kk = 0; kk < K; kk += 32) {
        __syncthreads();
#pragma unroll
        for (int i = 0; i < ACH; ++i) *(short8*)&As[sa_ro[i]] = av[i];
#pragma unroll
        for (int i = 0; i < 2; ++i)   *(short8*)&Bs[sb_ro[i]] = bv[i];
        __syncthreads();

        if (kk + 32 < K) {
#pragma unroll
            for (int i = 0; i < ACH; ++i) av[i] = *(const short8*)(A + sa_o[i] + kk + 32);
#pragma unroll
            for (int i = 0; i < 2; ++i)   bv[i] = *(const short8*)(Bt + sb_o[i] + kk + 32);
        }

        short8 af[MFR], bfr[4];
#pragma unroll
        for (int mi = 0; mi < MFR; ++mi) af[mi]  = *(const short8*)&As[a_off[mi]];
#pragma unroll
        for (int ni = 0; ni < 4; ++ni)   bfr[ni] = *(const short8*)&Bs[b_off[ni]];

#pragma unroll
        for (int mi = 0; mi < MFR; ++mi)
#pragma unroll
            for (int ni = 0; ni < 4; ++ni)
                acc[mi][ni] = __builtin_amdgcn_mfma_f32_16x16x32_bf16(af[mi], bfr[ni], acc[mi][ni], 0, 0, 0);
    }

#pragma unroll
    for (int mi = 0; mi < MFR; ++mi)
#pragma unroll
        for (int j = 0; j < 4; ++j) {
            int row = bm * BM + wr * (BM / 2) + mi * 16 + (l >> 4) * 4 + j;
            if (row < M) {
#pragma unroll
                for (int ni = 0; ni < 4; ++ni) {
                    int col = bn * 128 + wc * 64 + ni * 16 + (l & 15);
                    if (OUTMODE == 1)
                        ((ushort_t*)Cv)[(size_t)row * ldc + col] = f2b(acc[mi][ni][j]);
                    else
                        ((float*)Cv)[(size_t)row * ldc + col] = acc[mi][ni][j];
                }
            }
        }
}

// ---------------------------------------------------------------------------
// Split-bf16 dense GEMM (3-term, near-f32): C = (Ah+Al)[M,128] @ (Bh+Bl)t[512][128]
// f32 out, ldc=512. Used for q = x @ WQ.
// ---------------------------------------------------------------------------
__global__ __launch_bounds__(256) void gemm_split(const ushort_t* __restrict__ Ahg,
                                                  const ushort_t* __restrict__ Alg,
                                                  const ushort_t* __restrict__ Bhg,
                                                  const ushort_t* __restrict__ Blg,
                                                  float* __restrict__ C, int M)
{
    __shared__ ushort_t Ah[128 * LDSTRIDE], Al[128 * LDSTRIDE];
    __shared__ ushort_t Bh[128 * LDSTRIDE], Bl[128 * LDSTRIDE];

    const int tid = threadIdx.x;
    const int w = tid >> 6, l = tid & 63;
    const int bm = blockIdx.x, bn = blockIdx.y;
    const int wr = w >> 1, wc = w & 1;

    int s_ro[2]; size_t s_ao[2], s_bo[2];
#pragma unroll
    for (int i = 0; i < 2; ++i) {
        int c = tid + 256 * i;
        int row = c >> 2, slot = c & 3;
        s_ro[i] = row * LDSTRIDE + slot * 8;
        int grow = bm * 128 + row; if (grow >= M) grow = M - 1;
        s_ao[i] = (size_t)grow * 128 + slot * 8;
        s_bo[i] = (size_t)(bn * 128 + row) * 128 + slot * 8;
    }

    int a_off[4], b_off[4];
#pragma unroll
    for (int mi = 0; mi < 4; ++mi)
        a_off[mi] = (wr * 64 + mi * 16 + (l & 15)) * LDSTRIDE + (l >> 4) * 8;
#pragma unroll
    for (int ni = 0; ni < 4; ++ni)
        b_off[ni] = (wc * 64 + ni * 16 + (l & 15)) * LDSTRIDE + (l >> 4) * 8;

    f32x4 acc[4][4] = {};

    for (int kk = 0; kk < 128; kk += 32) {
        __syncthreads();
#pragma unroll
        for (int i = 0; i < 2; ++i) {
            *(short8*)&Ah[s_ro[i]] = *(const short8*)(Ahg + s_ao[i] + kk);
            *(short8*)&Al[s_ro[i]] = *(const short8*)(Alg + s_ao[i] + kk);
            *(short8*)&Bh[s_ro[i]] = *(const short8*)(Bhg + s_bo[i] + kk);
            *(short8*)&Bl[s_ro[i]] = *(const short8*)(Blg + s_bo[i] + kk);
        }
        __syncthreads();

        short8 ah[4], al[4], bh[4], bl[4];
#pragma unroll
        for (int mi = 0; mi < 4; ++mi) { ah[mi] = *(const short8*)&Ah[a_off[mi]];
                                         al[mi] = *(const short8*)&Al[a_off[mi]]; }
#pragma unroll
        for (int ni = 0; ni < 4; ++ni) { bh[ni] = *(const short8*)&Bh[b_off[ni]];
                                         bl[ni] = *(const short8*)&Bl[b_off[ni]]; }

#pragma unroll
        for (int mi = 0; mi < 4; ++mi)
#pragma unroll
            for (int ni = 0; ni < 4; ++ni) {
                acc[mi][ni] = __builtin_amdgcn_mfma_f32_16x16x32_bf16(ah[mi], bh[ni], acc[mi][ni], 0, 0, 0);
                acc[mi][ni] = __builtin_amdgcn_mfma_f32_16x16x32_bf16(ah[mi], bl[ni], acc[mi][ni], 0, 0, 0);
                acc[mi][ni] = __builtin_amdgcn_mfma_f32_16x16x32_bf16(al[mi], bh[ni], acc[mi][ni], 0, 0, 0);
            }
    }

#pragma unroll
    for (int mi = 0; mi < 4; ++mi)
#pragma unroll
        for (int j = 0; j < 4; ++j) {
            int row = bm * 128 + wr * 64 + mi * 16 + (l >> 4) * 4 + j;
            if (row < M) {
#pragma unroll
                for (int ni = 0; ni < 4; ++ni) {
                    int col = bn * 128 + wc * 64 + ni * 16 + (l & 15);
                    C[(size_t)row * 512 + col] = acc[mi][ni][j];
                }
            }
        }
}

// ---------------------------------------------------------------------------
// Fused scores, ONE launch: grid (edge-tile, head, rel). Per block:
//   k-chunk = (x_hi+x_lo)[src] @ (W_hi+W_lo) for ONE head (3-term split MFMA)
//   s[e,h] = SCALE * dot(k, q_f32[dst, h*128:...]); flag |s|<TAU.
// ---------------------------------------------------------------------------
__global__ __launch_bounds__(256) void scores_fused(const ushort_t* __restrict__ xh,
                                                    const ushort_t* __restrict__ xl,
                                                    const ushort_t* __restrict__ WKth,
                                                    const ushort_t* __restrict__ WKtl,
                                                    const float* __restrict__ q,
                                                    const int* __restrict__ src,
                                                    const int* __restrict__ dst,
                                                    float* __restrict__ scores,
                                                    int* __restrict__ flagcnt,
                                                    int* __restrict__ fids)
{
    __shared__ ushort_t Ah[128 * LDSTRIDE], Al[128 * LDSTRIDE];
    __shared__ ushort_t Bh[128 * LDSTRIDE], Bl[128 * LDSTRIDE];
    __shared__ float sc_red[128][2];

    const int tid = threadIdx.x;
    const int w = tid >> 6, l = tid & 63;
    const int bm = blockIdx.x;
    const int nc = blockIdx.y;          // head
    const int r  = blockIdx.z;          // relation
    const int wr = w >> 1, wc = w & 1;

    const int* srcr = src + r * NEDGE;
    const int* dstr = dst + r * NEDGE;
    const ushort_t* Wh = WKth + (size_t)r * HDIM * DIM;
    const ushort_t* Wl = WKtl + (size_t)r * HDIM * DIM;
    float* sc_out = scores + (size_t)r * NEDGE * HEADS;

    int s_ro[2], s_row[2], s_slot[2];
    size_t s_ao[2], s_bo[2];
#pragma unroll
    for (int i = 0; i < 2; ++i) {
        int c = tid + 256 * i;
        s_row[i] = c >> 2; s_slot[i] = c & 3;
        s_ro[i] = s_row[i] * LDSTRIDE + s_slot[i] * 8;
        int e = bm * 128 + s_row[i]; if (e >= NEDGE) e = NEDGE - 1;
        s_ao[i] = (size_t)srcr[e] * 128 + s_slot[i] * 8;
        s_bo[i] = (size_t)(nc * 128 + s_row[i]) * 128 + s_slot[i] * 8;
    }

    int a_off[4], b_off[4];
#pragma unroll
    for (int mi = 0; mi < 4; ++mi)
        a_off[mi] = (wr * 64 + mi * 16 + (l & 15)) * LDSTRIDE + (l >> 4) * 8;
#pragma unroll
    for (int ni = 0; ni < 4; ++ni)
        b_off[ni] = (wc * 64 + ni * 16 + (l & 15)) * LDSTRIDE + (l >> 4) * 8;

    f32x4 acc[4][4] = {};

    // prefetch k-slice 0
    short8 vah[2], val[2], vbh[2], vbl[2];
#pragma unroll
    for (int i = 0; i < 2; ++i) {
        vah[i] = *(const short8*)(xh + s_ao[i]);
        val[i] = *(const short8*)(xl + s_ao[i]);
        vbh[i] = *(const short8*)(Wh + s_bo[i]);
        vbl[i] = *(const short8*)(Wl + s_bo[i]);
    }

    for (int kk = 0; kk < 128; kk += 32) {
        __syncthreads();
#pragma unroll
        for (int i = 0; i < 2; ++i) {
            *(short8*)&Ah[s_ro[i]] = vah[i];
            *(short8*)&Al[s_ro[i]] = val[i];
            *(short8*)&Bh[s_ro[i]] = vbh[i];
            *(short8*)&Bl[s_ro[i]] = vbl[i];
        }
        __syncthreads();

        if (kk + 32 < 128) {
#pragma unroll
            for (int i = 0; i < 2; ++i) {
                vah[i] = *(const short8*)(xh + s_ao[i] + kk + 32);
                val[i] = *(const short8*)(xl + s_ao[i] + kk + 32);
                vbh[i] = *(const short8*)(Wh + s_bo[i] + kk + 32);
                vbl[i] = *(const short8*)(Wl + s_bo[i] + kk + 32);
            }
        }

        short8 ah[4], al[4], bh[4], bl[4];
#pragma unroll
        for (int mi = 0; mi < 4; ++mi) { ah[mi] = *(const short8*)&Ah[a_off[mi]];
                                         al[mi] = *(const short8*)&Al[a_off[mi]]; }
#pragma unroll
        for (int ni = 0; ni < 4; ++ni) { bh[ni] = *(const short8*)&Bh[b_off[ni]];
                                         bl[ni] = *(const short8*)&Bl[b_off[ni]]; }
#pragma unroll
        for (int mi = 0; mi < 4; ++mi)
#pragma unroll
            for (int ni = 0; ni < 4; ++ni) {
                acc[mi][ni] = __builtin_amdgcn_mfma_f32_16x16x32_bf16(ah[mi], bh[ni], acc[mi][ni], 0, 0, 0);
                acc[mi][ni] = __builtin_amdgcn_mfma_f32_16x16x32_bf16(ah[mi], bl[ni], acc[mi][ni], 0, 0, 0);
                acc[mi][ni] = __builtin_amdgcn_mfma_f32_16x16x32_bf16(al[mi], bh[ni], acc[mi][ni], 0, 0, 0);
            }
    }

    // dot k-fragments with q[dst]
#pragma unroll
    for (int mi = 0; mi < 4; ++mi)
#pragma unroll
        for (int j = 0; j < 4; ++j) {
            int e_loc = wr * 64 + mi * 16 + (l >> 4) * 4 + j;
            int e = bm * 128 + e_loc; int ec = (e < NEDGE) ? e : NEDGE - 1;
            int d = dstr[ec];
            const float* qr = q + (size_t)d * HDIM + nc * 128 + wc * 64 + (l & 15);
            float p = acc[mi][0][j] * qr[0]  + acc[mi][1][j] * qr[16]
                    + acc[mi][2][j] * qr[32] + acc[mi][3][j] * qr[48];
            p += __shfl_xor(p, 1); p += __shfl_xor(p, 2);
            p += __shfl_xor(p, 4); p += __shfl_xor(p, 8);
            if ((l & 15) == 0) sc_red[e_loc][wc] = p;
        }
    __syncthreads();

    if (tid < 128) {
        int e = bm * 128 + tid;
        if (e < NEDGE) {
            float s = (sc_red[tid][0] + sc_red[tid][1]) * SCALE;
            sc_out[(size_t)e * HEADS + nc] = s;
            if (fabsf(s) < TAU) {
                int pos = atomicAdd(flagcnt, 1);
                if (pos < FLAG_CAP) fids[pos] = (r * NEDGE + e) * HEADS + nc;
            }
        }
    }
}

// ---------------------------------------------------------------------------
// Exact f32 repair of near-zero scores.
// ---------------------------------------------------------------------------
__global__ __launch_bounds__(256) void repair_kernel(const float* __restrict__ x,
                                                     const float* __restrict__ WQ,
                                                     const float* __restrict__ WK,
                                                     const int* __restrict__ src,
                                                     const int* __restrict__ dst,
                                                     const int* __restrict__ flagcnt,
                                                     const int* __restrict__ fids,
                                                     float* __restrict__ scores)
{
    int wid = blockIdx.x * 4 + (threadIdx.x >> 6);
    int l = threadIdx.x & 63;
    int nf = *flagcnt; if (nf > FLAG_CAP) nf = FLAG_CAP;
    if (wid >= nf) return;
    int p = fids[wid];
    int h = p & 3; int eg = p >> 2; int r = eg / NEDGE;
    int s = src[eg], d = dst[eg];
    const float* xs = x + (size_t)s * DIM;
    const float* xd = x + (size_t)d * DIM;
    const float* wq = WQ + h * DIM;
    const float* wk = WK + (size_t)r * DIM * HDIM + h * DIM;

    float tot = 0.f;
#pragma unroll 1
    for (int j = 0; j < 2; ++j) {
        int c = j * 64 + l;
        float qc = 0.f, kc = 0.f;
        for (int dd = 0; dd < DIM; ++dd) {
            qc = fmaf(xd[dd], wq[(size_t)dd * HDIM + c], qc);
            kc = fmaf(xs[dd], wk[(size_t)dd * HDIM + c], kc);
        }
        tot = fmaf(qc, kc, tot);
    }
    tot += __shfl_xor(tot, 1);  tot += __shfl_xor(tot, 2);
    tot += __shfl_xor(tot, 4);  tot += __shfl_xor(tot, 8);
    tot += __shfl_xor(tot, 16); tot += __shfl_xor(tot, 32);
    if (l == 0) scores[p] = tot * SCALE;
}

// ---------------------------------------------------------------------------
// numer = relu(s)^2 + eps (in place) ; atomic denom
// ---------------------------------------------------------------------------
__global__ __launch_bounds__(256) void numer_denom(float* __restrict__ scores,
                                                   const int* __restrict__ dst,
                                                   float* __restrict__ denom)
{
    int p = blockIdx.x * 256 + threadIdx.x;
    if (p < NETOT * HEADS) {
        float s = scores[p];
        float m = fmaxf(s, 0.f);
        float nu = m * m + EPS_F;
        scores[p] = nu;
        atomicAdd(&denom[dst[p >> 2] * HEADS + (p & 3)], nu);
    }
}

// ---------------------------------------------------------------------------
// prep kernels
// ---------------------------------------------------------------------------
__global__ __launch_bounds__(256) void cvt_x_split(const float* __restrict__ x,
                                                   ushort_t* __restrict__ xh,
                                                   ushort_t* __restrict__ xl)
{
    int i = (blockIdx.x * 256 + threadIdx.x) * 4;
    float4 v = *reinterpret_cast<const float4*>(x + i);
    ushort_t h0 = f2b(v.x), h1 = f2b(v.y), h2 = f2b(v.z), h3 = f2b(v.w);
    ushort4v oh = {h0, h1, h2, h3};
    ushort4v ol = {f2b(v.x - b2f(h0)), f2b(v.y - b2f(h1)),
                   f2b(v.z - b2f(h2)), f2b(v.w - b2f(h3))};
    *reinterpret_cast<ushort4v*>(xh + i) = oh;
    *reinterpret_cast<ushort4v*>(xl + i) = ol;
}

// split transpose: hi/lo pair. out[C][R] = transpose(in[R][C] f32)
__global__ __launch_bounds__(256) void transpose_cvt_split(const float* __restrict__ in,
                                                           ushort_t* __restrict__ oh,
                                                           ushort_t* __restrict__ ol,
                                                           int R, int C)
{
    __shared__ float t[32][33];
    int x = threadIdx.x & 31, y0 = threadIdx.x >> 5;
    int br = blockIdx.y, bc = blockIdx.x;
#pragma unroll
    for (int k = 0; k < 4; ++k)
        t[y0 + k * 8][x] = in[(size_t)(br * 32 + y0 + k * 8) * C + bc * 32 + x];
    __syncthreads();
#pragma unroll
    for (int k = 0; k < 4; ++k) {
        int c = bc * 32 + y0 + k * 8;
        float v = t[x][y0 + k * 8];
        ushort_t hv = f2b(v);
        oh[(size_t)c * R + br * 32 + x] = hv;
        ol[(size_t)c * R + br * 32 + x] = f2b(v - b2f(hv));
    }
}

// ---------------------------------------------------------------------------
// W2 composite: W2t[j][h*384 + r*128 + d] = sum_c WV[r][d][h*128+c] * WO[h*128+c][j]
// ---------------------------------------------------------------------------
__global__ __launch_bounds__(256) void w2_kernel(const float* __restrict__ WV,
                                                 const float* __restrict__ WO,
                                                 ushort_t* __restrict__ W2t)
{
    int j = threadIdx.x & 127;
    int hk = blockIdx.x * 2 + (threadIdx.x >> 7);   // 0..1535
    int h = hk / 384, kk = hk % 384;
    int r = kk >> 7, d = kk & 127;
    const float* wv = WV + (size_t)r * DIM * HDIM + (size_t)d * HDIM + h * DIM;
    const float* wo = WO + (size_t)(h * DIM) * DIM + j;
    float acc = 0.f;
#pragma unroll 4
    for (int c = 0; c < DIM; ++c)
        acc = fmaf(wv[c], wo[(size_t)c * DIM], acc);
    W2t[(size_t)j * 1536 + hk] = f2b(acc);
}

// ---------------------------------------------------------------------------
// CSR build: count, hierarchical scan, fill.
// ---------------------------------------------------------------------------
__global__ __launch_bounds__(256) void csr_count(const int* __restrict__ dst, int* __restrict__ cnt)
{
    int e = blockIdx.x * 256 + threadIdx.x;
    if (e < NETOT) atomicAdd(&cnt[dst[e]], 1);
}

__global__ __launch_bounds__(256) void scan_blksum(const int* __restrict__ cnt,
                                                   int* __restrict__ blksum)
{
    __shared__ int red[4];
    int tid = threadIdx.x, lane = tid & 63, wave = tid >> 6;
    int i = blockIdx.x * 256 + tid;
    int v = (i < N_NODES) ? cnt[i] : 0;
#pragma unroll
    for (int off = 32; off > 0; off >>= 1) v += __shfl_down(v, off);
    if (lane == 0) red[wave] = v;
    __syncthreads();
    if (tid == 0) blksum[blockIdx.x] = red[0] + red[1] + red[2] + red[3];
}

__global__ __launch_bounds__(256) void scan_top(const int* __restrict__ blksum,
                                                int* __restrict__ blkoff,
                                                int* __restrict__ row_ptr)
{
    __shared__ int s[256];
    int t = threadIdx.x;
    int v = (t < NSCAN_BLK) ? blksum[t] : 0;
    s[t] = v;
    __syncthreads();
    for (int off = 1; off < 256; off <<= 1) {
        int u = (t >= off) ? s[t - off] : 0;
        __syncthreads();
        s[t] += u;
        __syncthreads();
    }
    if (t < NSCAN_BLK) blkoff[t] = s[t] - v;   // exclusive
    if (t == NSCAN_BLK - 1) row_ptr[N_NODES] = s[t];
}

__global__ __launch_bounds__(256) void scan_fin(const int* __restrict__ cnt,
                                                const int* __restrict__ blkoff,
                                                int* __restrict__ row_ptr,
                                                int* __restrict__ cursor)
{
    __shared__ int s[256];
    int t = threadIdx.x, i = blockIdx.x * 256 + t;
    int v = (i < N_NODES) ? cnt[i] : 0;
    s[t] = v;
    __syncthreads();
    for (int off = 1; off < 256; off <<= 1) {
        int u = (t >= off) ? s[t - off] : 0;
        __syncthreads();
        s[t] += u;
        __syncthreads();
    }
    if (i < N_NODES) {
        int val = blkoff[blockIdx.x] + s[t] - v;
        row_ptr[i] = val;
        cursor[i]  = val;
    }
}

__global__ __launch_bounds__(256) void csr_fill(const int* __restrict__ dst,
                                                int* __restrict__ cursor,
                                                int* __restrict__ eids)
{
    int e = blockIdx.x * 256 + threadIdx.x;
    if (e < NETOT) {
        int pos = atomicAdd(&cursor[dst[e]], 1);
        eids[pos] = e;
    }
}

// ---------------------------------------------------------------------------
// agg_all: one wave per node, ALL 4 heads in one pass (x gathered once).
// ---------------------------------------------------------------------------
__global__ __launch_bounds__(256) void agg_all(const float* __restrict__ x,
                                               const float* __restrict__ numer,
                                               const float* __restrict__ denom,
                                               const int* __restrict__ row_ptr,
                                               const int* __restrict__ eids,
                                               const int* __restrict__ src,
                                               ushort_t* __restrict__ y)
{
    const int wave = threadIdx.x >> 6, lane = threadIdx.x & 63;
    const int n = blockIdx.x * 4 + wave;
    if (n >= N_NODES) return;

    const int beg = row_ptr[n], end = row_ptr[n + 1];
    float acc[NREL][HEADS][2] = {};

    if (beg < end) {
        float4 dn = *reinterpret_cast<const float4*>(&denom[n * HEADS]);
        float di[HEADS] = {1.f / dn.x, 1.f / dn.y, 1.f / dn.z, 1.f / dn.w};
        for (int i = beg; i < end; ++i) {
            int e = eids[i];
            int s = src[e];
            float4 nu = *reinterpret_cast<const float4*>(&numer[(size_t)e * HEADS]);
            float wv[HEADS] = {nu.x * di[0], nu.y * di[1], nu.z * di[2], nu.w * di[3]};
            float x0 = x[(size_t)s * DIM + lane];
            float x1 = x[(size_t)s * DIM + 64 + lane];
            int r = e / NEDGE;   // wave-uniform per iteration
            if (r == 0) {
#pragma unroll
                for (int h = 0; h < HEADS; ++h) {
                    acc[0][h][0] = fmaf(wv[h], x0, acc[0][h][0]);
                    acc[0][h][1] = fmaf(wv[h], x1, acc[0][h][1]);
                }
            } else if (r == 1) {
#pragma unroll
                for (int h = 0; h < HEADS; ++h) {
                    acc[1][h][0] = fmaf(wv[h], x0, acc[1][h][0]);
                    acc[1][h][1] = fmaf(wv[h], x1, acc[1][h][1]);
                }
            } else {
#pragma unroll
                for (int h = 0; h < HEADS; ++h) {
                    acc[2][h][0] = fmaf(wv[h], x0, acc[2][h][0]);
                    acc[2][h][1] = fmaf(wv[h], x1, acc[2][h][1]);
                }
            }
        }
    }

    ushort_t* yr = y + (size_t)n * 1536;
#pragma unroll
    for (int h = 0; h < HEADS; ++h)
#pragma unroll
        for (int r = 0; r < NREL; ++r) {
            yr[h * 384 + r * 128 + lane]      = f2b(acc[r][h][0]);
            yr[h * 384 + r * 128 + 64 + lane] = f2b(acc[r][h][1]);
        }
}

// ---------------------------------------------------------------------------
extern "C" void kernel_launch(void* const* d_in, const int* in_sizes, int n_in,
                              void* d_out, int out_size, void* d_ws, size_t ws_size,
                              hipStream_t stream)
{
    const float* x   = (const float*)d_in[0];
    const float* WQ  = (const float*)d_in[1];
    const float* WK  = (const float*)d_in[2];
    const float* WV  = (const float*)d_in[3];
    const float* WO  = (const float*)d_in[4];
    const int*   src = (const int*)d_in[5];
    const int*   dst = (const int*)d_in[6];
    float* out = (float*)d_out;

    char* ws = (char*)d_ws;
    float*    scores  = (float*)(ws);                    // 2,400,000 (later numer in place)
    float*    denom   = (float*)(ws + 2400000);          //   800,000
    int*      cnt     = (int*)(ws + 3200000);            //   200,000
    int*      row_ptr = (int*)(ws + 3400000);            //   200,004
    int*      cursor  = (int*)(ws + 3600016);            //   200,000
    int*      eids    = (int*)(ws + 3800016);            //   600,000
    int*      flagcnt = (int*)(ws + 4400016);            //        16
    int*      fids    = (int*)(ws + 4400032);            //   131,072
    int*      blksum  = (int*)(ws + 4531104);
    int*      blkoff  = (int*)(ws + 4532144);
    ushort_t* WQt_hi  = (ushort_t*)(ws + 4533184);       //   131,072
    ushort_t* WQt_lo  = (ushort_t*)(ws + 4664256);       //   131,072
    ushort_t* WKt_hi  = (ushort_t*)(ws + 4795328);       //   393,216 [3][512][128]
    ushort_t* WKt_lo  = (ushort_t*)(ws + 5188544);       //   393,216
    ushort_t* W2t     = (ushort_t*)(ws + 5581760);       //   393,216 [128][1536]
    // big overlaid region, base 6,000,000:
    //   phase A: x_hi [6.0M,18.8M) x_lo [18.8M,31.6M) q_f32 [31.6M,134.0M)
    //   phase B: y_cat [6.0M,159.6M) bf16 [N][1536]
    ushort_t* x_hi  = (ushort_t*)(ws + 6000000);
    ushort_t* x_lo  = (ushort_t*)(ws + 18800000);
    float*    q_f32 = (float*)(ws + 31600000);
    ushort_t* y_cat = (ushort_t*)(ws + 6000000);

    dim3 blk(256);

    // ---- prep ----
    cvt_x_split<<<dim3(6250), blk, 0, stream>>>(x, x_hi, x_lo);
    transpose_cvt_split<<<dim3(16, 4), blk, 0, stream>>>(WQ, WQt_hi, WQt_lo, 128, 512);
    for (int r = 0; r < NREL; ++r)
        transpose_cvt_split<<<dim3(16, 4), blk, 0, stream>>>(WK + (size_t)r * DIM * HDIM,
                                                             WKt_hi + (size_t)r * HDIM * DIM,
                                                             WKt_lo + (size_t)r * HDIM * DIM, 128, 512);
    w2_kernel<<<dim3(768), blk, 0, stream>>>(WV, WO, W2t);

    hipMemsetAsync(cnt,     0, (size_t)N_NODES * sizeof(int), stream);
    hipMemsetAsync(denom,   0, (size_t)N_NODES * HEADS * sizeof(float), stream);
    hipMemsetAsync(flagcnt, 0, 16, stream);

    // ---- CSR by dst (parallel scan) ----
    csr_count<<<dim3((NETOT + 255) / 256), blk, 0, stream>>>(dst, cnt);
    scan_blksum<<<dim3(NSCAN_BLK), blk, 0, stream>>>(cnt, blksum);
    scan_top<<<dim3(1), blk, 0, stream>>>(blksum, blkoff, row_ptr);
    scan_fin<<<dim3(NSCAN_BLK), blk, 0, stream>>>(cnt, blkoff, row_ptr, cursor);
    csr_fill<<<dim3((NETOT + 255) / 256), blk, 0, stream>>>(dst, cursor, eids);

    const int MB128 = (N_NODES + 127) / 128;   // 391
    const int MB64  = (N_NODES + 63) / 64;     // 782

    // ---- q = x @ WQ, near-f32 via 3-term split ----
    gemm_split<<<dim3(MB128, 4), blk, 0, stream>>>(x_hi, x_lo, WQt_hi, WQt_lo, q_f32, N_NODES);

    // ---- fused scores: single launch over (edge-tile, head, rel) ----
    scores_fused<<<dim3(MB128, HEADS, NREL), blk, 0, stream>>>(
        x_hi, x_lo, WKt_hi, WKt_lo, q_f32, src, dst, scores, flagcnt, fids);

    // ---- exact f32 repair of near-zero scores ----
    repair_kernel<<<dim3(FLAG_CAP / 4), blk, 0, stream>>>(x, WQ, WK, src, dst,
                                                          flagcnt, fids, scores);

    // ---- numer (in place) + denom ----
    numer_denom<<<dim3((NETOT * HEADS + 255) / 256), blk, 0, stream>>>(scores, dst, denom);

    // ---- aggregation: all 4 heads in one pass -> y_cat [N][1536] ----
    agg_all<<<dim3((N_NODES + 3) / 4), blk, 0, stream>>>(
        x, scores, denom, row_ptr, eids, src, y_cat);

    // ---- out = y_cat @ W2 (one MFMA GEMM, BM=64 for occupancy) ----
    gemm_mfma<0, 64><<<dim3(MB64, 1), blk, 0, stream>>>(y_cat, W2t, out, N_NODES, 1536, DIM);
}